// Round 5
// baseline (2525.677 us; speedup 1.0000x reference)
//
#include <hip/hip_runtime.h>
#include <math.h>

#define NN 10000
#define NE 320000
#define NEP (NE + 64)      // padded ebuf row stride (breaks 1KiB channel alignment)
#define PI_F 3.14159265358979323846f

typedef __attribute__((ext_vector_type(8))) short short8x;
typedef __attribute__((ext_vector_type(8))) unsigned short ushort8x;
typedef __attribute__((ext_vector_type(4))) float float4x;

__device__ __forceinline__ unsigned short f2b(float f) {
    unsigned b = __float_as_uint(f);
    return (unsigned short)((b + 0x7FFFu + ((b >> 16) & 1u)) >> 16);
}
__device__ __forceinline__ float b2f(unsigned short u) {
    return __uint_as_float(((unsigned)u) << 16);
}

// ---------------- K = Newton-Schulz semi-unitary (16x2) ----------------
__global__ void k_newton_kernel(const float* __restrict__ PU, float* __restrict__ Kout)
{
    if (threadIdx.x != 0 || blockIdx.x != 0) return;
    float K[32];
    float nrm = 0.f;
    for (int i = 0; i < 32; ++i) { K[i] = PU[i]; nrm += K[i]*K[i]; }
    float inv = 1.0f / sqrtf(nrm);
    for (int i = 0; i < 32; ++i) K[i] *= inv;
    for (int it = 0; it < 10; ++it) {
        float m00 = 0.f, m01 = 0.f, m11 = 0.f;
        for (int u = 0; u < 16; ++u) {
            float a = K[2*u], b = K[2*u+1];
            m00 += a*a; m01 += a*b; m11 += b*b;
        }
        for (int u = 0; u < 16; ++u) {
            float a = K[2*u], b = K[2*u+1];
            K[2*u]   = 1.5f*a - 0.5f*(a*m00 + b*m01);
            K[2*u+1] = 1.5f*b - 0.5f*(a*m01 + b*m11);
        }
    }
    for (int i = 0; i < 32; ++i) Kout[i] = K[i];
}

// ---------------- x_pad init: (N,6) -> (N,8) ----------------
__global__ void init_xpad_kernel(const float* __restrict__ x, float* __restrict__ xp)
{
    int tid = blockIdx.x*blockDim.x + threadIdx.x;
    if (tid >= NN*8) return;
    int n = tid >> 3, c = tid & 7;
    xp[tid] = (c < 6) ? x[n*6 + c] : 0.f;
}

// ---------------- yv init ----------------
__global__ void init_yv_kernel(const float* __restrict__ x, const float* __restrict__ K,
                               float* __restrict__ yv0, float* __restrict__ yv1)
{
    int tid = blockIdx.x*blockDim.x + threadIdx.x;
    if (tid >= NN*48) return;
    int n = tid/48, j = tid%48, u = j/3, m = j%3;
    float v = K[2*u]*x[n*6+m] + K[2*u+1]*x[n*6+3+m];
    yv0[tid] = v; yv1[tid] = v;
}

// ---------------- per-type effective weights ----------------
__global__ void build_eff_kernel(const float* __restrict__ W, const float* __restrict__ emb,
                                 float* __restrict__ out, int O, int I, float scale, int total)
{
    int tid = blockIdx.x*blockDim.x + threadIdx.x;
    if (tid >= total) return;
    int o = tid % O; int r = tid / O;
    int i = r % I; r /= I;
    int t = r % 100; int l = r / 100;
    const float* w  = W + (((size_t)l*O + o)*I + i)*32;
    const float* em = emb + (size_t)t*32;
    float acc = 0.f;
    #pragma unroll
    for (int e = 0; e < 32; ++e) acc += w[e]*em[e];
    out[tid] = acc*scale;
}

// ---------------- transpose (L,O,I) -> (L,I,O), scaled ----------------
__global__ void transpose_kernel(const float* __restrict__ W, float* __restrict__ out,
                                 int O, int I, float scale, int total)
{
    int tid = blockIdx.x*blockDim.x + threadIdx.x;
    if (tid >= total) return;
    int o = tid % O; int r = tid / O;
    int i = r % I; int l = r / I;
    out[tid] = W[((size_t)l*O + o)*I + i]*scale;
}

// ---------------- f32 -> bf16 cast ----------------
__global__ void cast_bf16_kernel(const float* __restrict__ in, unsigned short* __restrict__ out, int total)
{
    int tid = blockIdx.x*blockDim.x + threadIdx.x;
    if (tid < total) out[tid] = f2b(in[tid]);
}

// ---------------- counting sort by dst ----------------
__global__ void hist_kernel(const int* __restrict__ dst, int* __restrict__ deg)
{
    int e = blockIdx.x*256 + threadIdx.x;
    if (e < NE) atomicAdd(&deg[dst[e]], 1);
}

__global__ __launch_bounds__(256) void scan_kernel(const int* __restrict__ deg,
                                                   int* __restrict__ segoff,
                                                   int* __restrict__ cursor)
{
    __shared__ int part[256];
    int tid = threadIdx.x;
    int base = tid*40;
    int s = 0;
    for (int i = 0; i < 40; ++i) { int idx = base+i; if (idx < NN) s += deg[idx]; }
    part[tid] = s;
    __syncthreads();
    for (int o = 1; o < 256; o <<= 1) {
        int v = (tid >= o) ? part[tid-o] : 0;
        __syncthreads();
        part[tid] += v;
        __syncthreads();
    }
    int excl = part[tid] - s;
    for (int i = 0; i < 40; ++i) {
        int idx = base+i;
        if (idx < NN) { segoff[idx] = excl; cursor[idx] = excl; excl += deg[idx]; }
        else if (idx == NN) { segoff[NN] = excl; }
    }
}

__global__ void scatter_kernel(const int* __restrict__ src, const int* __restrict__ dst,
                               int* __restrict__ cursor,
                               int* __restrict__ srcs, int* __restrict__ dsts)
{
    int e = blockIdx.x*256 + threadIdx.x;
    if (e >= NE) return;
    int d = dst[e];
    int p = atomicAdd(&cursor[d], 1);
    srcs[p] = src[e]; dsts[p] = d;
}

// ---------------- lin1 FCTP ----------------
__global__ __launch_bounds__(128) void node_lin1_kernel(
    const float* __restrict__ ys, const float* __restrict__ yv,
    const int* __restrict__ types,
    const float* __restrict__ lin1sT, const float* __restrict__ lin1vT,
    float* __restrict__ fs, float* __restrict__ fvv)
{
    int n = blockIdx.x;
    int lane = threadIdx.x;
    __shared__ float ys_l[64];
    __shared__ float yv_l[48];
    int t = types[n];
    if (lane < 64) ys_l[lane] = ys[n*64 + lane];
    else if (lane < 112) yv_l[lane-64] = yv[n*48 + (lane-64)];
    __syncthreads();
    if (lane < 64) {
        const float* W = lin1sT + (size_t)t*4096;
        float acc = 0.f;
        #pragma unroll
        for (int i = 0; i < 64; ++i) acc += ys_l[i]*W[i*64 + lane];
        fs[n*64 + lane] = acc;
    } else if (lane < 112) {
        int j = lane - 64, o = j/3, m = j%3;
        const float* W = lin1vT + (size_t)t*256;
        float acc = 0.f;
        #pragma unroll
        for (int i = 0; i < 16; ++i) acc += yv_l[i*3+m]*W[i*16 + o];
        fvv[n*48 + j] = acc;
    }
}

// ---------------- pass 1: geometry + radial MLP -> h2 (bf16), af (edge attrs) ----------------
__global__ __launch_bounds__(256) void edge_mlp_kernel(
    const float* __restrict__ xp,
    const int* __restrict__ srcs, const int* __restrict__ dsts,
    const float* __restrict__ W1T, const float* __restrict__ b1,
    const float* __restrict__ W2T, const float* __restrict__ b2,
    unsigned short* __restrict__ h2bf, float* __restrict__ af)
{
    int p = blockIdx.x*256 + threadIdx.x;   // grid == NE exactly
    int s = srcs[p], d = dsts[p];
    const float4* xs4 = (const float4*)(xp + (size_t)s*8);
    const float4* xd4 = (const float4*)(xp + (size_t)d*8);
    float4 xsa = xs4[0], xsb = xs4[1];
    float4 xda = xd4[0], xdb = xd4[1];
    float a0[3], a1[3], ef[16];
    {
        float d0 = xsa.x-xda.x, d1 = xsa.y-xda.y, d2 = xsa.z-xda.z;
        float r = sqrtf(d0*d0 + d1*d1 + d2*d2);
        float invr = 1.0f/r;
        float u = 0.8f*r - 2.0f;
        float cut = (u > 0.f) ? 0.f : ((u < -1.f) ? 1.f : 0.5f*(1.f - __cosf(PI_F*u)));
        float sc = 1.7320508075688772f*cut*invr;
        a0[0] = sc*d0; a0[1] = sc*d1; a0[2] = sc*d2;
        float fsc = 2.5298221281347035f*invr;
        #pragma unroll
        for (int k = 0; k < 8; ++k) ef[k] = fsc*__sinf((k+1)*1.2566370614359172f*r);
    }
    {
        float d0 = xsa.w-xda.w, d1 = xsb.x-xdb.x, d2 = xsb.y-xdb.y;
        float r = sqrtf(d0*d0 + d1*d1 + d2*d2);
        float invr = 1.0f/r;
        float u = 0.8f*r - 2.0f;
        float cut = (u > 0.f) ? 0.f : ((u < -1.f) ? 1.f : 0.5f*(1.f - __cosf(PI_F*u)));
        float sc = 1.7320508075688772f*cut*invr;
        a1[0] = sc*d0; a1[1] = sc*d1; a1[2] = sc*d2;
        float fsc = 2.5298221281347035f*invr;
        #pragma unroll
        for (int k = 0; k < 8; ++k) ef[8+k] = fsc*__sinf((k+1)*1.2566370614359172f*r);
    }
    // store edge attrs
    {
        float4* af4 = (float4*)(af + (size_t)p*8);
        float4 t0; t0.x = a0[0]; t0.y = a0[1]; t0.z = a0[2]; t0.w = a1[0];
        float4 t1; t1.x = a1[1]; t1.y = a1[2]; t1.z = 0.f; t1.w = 0.f;
        af4[0] = t0; af4[1] = t1;
    }
    float h1[64];
    #pragma unroll
    for (int j = 0; j < 64; ++j) {
        const float* w = W1T + j*16;
        float acc = b1[j];
        #pragma unroll
        for (int k = 0; k < 16; ++k) acc += ef[k]*w[k];
        h1[j] = acc/(1.f + __expf(-acc));
    }
    unsigned wpk[32];
    #pragma unroll
    for (int j = 0; j < 64; j += 2) {
        float acc0, acc1;
        {
            const float* w = W2T + j*64;
            float a = b2[j];
            #pragma unroll
            for (int k = 0; k < 64; ++k) a += h1[k]*w[k];
            acc0 = a/(1.f + __expf(-a));
        }
        {
            const float* w = W2T + (j+1)*64;
            float a = b2[j+1];
            #pragma unroll
            for (int k = 0; k < 64; ++k) a += h1[k]*w[k];
            acc1 = a/(1.f + __expf(-a));
        }
        wpk[j>>1] = (unsigned)f2b(acc0) | ((unsigned)f2b(acc1) << 16);
    }
    uint4* dst = (uint4*)(h2bf + (size_t)p*64);
    #pragma unroll
    for (int g = 0; g < 8; ++g) {
        uint4 q;
        q.x = wpk[4*g+0]; q.y = wpk[4*g+1]; q.z = wpk[4*g+2]; q.w = wpk[4*g+3];
        dst[g] = q;
    }
}

// ---------------- pass 2 (fused): MFMA w = h2 @ W3 -> LDS -> TP -> ebuf ----------------
__global__ __launch_bounds__(256) void wgemm_tp_kernel(
    const unsigned short* __restrict__ h2bf,
    const unsigned short* __restrict__ w3bf,   // [192][64] bf16 rows (n-major, k-contig)
    const float* __restrict__ b3,
    const int* __restrict__ srcs,
    const float* __restrict__ fs, const float* __restrict__ fvv,
    const float* __restrict__ af,
    unsigned short* __restrict__ ebuf)
{
    __shared__ float wtile[64*193];
    int lane = threadIdx.x & 63;
    int wid  = threadIdx.x >> 6;
    int eblk = blockIdx.x * 64;

    // ---- MFMA phase: wave wid computes 16 edges x 192 comps ----
    {
        int e0 = eblk + 16*wid;
        int row16 = lane & 15, quad = lane >> 4;
        float4x acc[12];
        #pragma unroll
        for (int nt = 0; nt < 12; ++nt) acc[nt] = (float4x){0.f,0.f,0.f,0.f};
        #pragma unroll
        for (int ks = 0; ks < 2; ++ks) {
            short8x a = *(const short8x*)(h2bf + ((size_t)(e0 + row16))*64 + ks*32 + quad*8);
            #pragma unroll
            for (int nt = 0; nt < 12; ++nt) {
                short8x b = *(const short8x*)(w3bf + ((size_t)(nt*16 + row16))*64 + ks*32 + quad*8);
                acc[nt] = __builtin_amdgcn_mfma_f32_16x16x32_bf16(a, b, acc[nt], 0, 0, 0);
            }
        }
        // C layout: row(edge) = quad*4 + r, col(n) = lane&15
        #pragma unroll
        for (int nt = 0; nt < 12; ++nt) {
            #pragma unroll
            for (int r = 0; r < 4; ++r) {
                wtile[(16*wid + quad*4 + r)*193 + nt*16 + row16] = acc[nt][r];
            }
        }
    }
    __syncthreads();

    // ---- TP phase: thread (e = lane, part = wid) ----
    int p = eblk + lane;
    int s = srcs[p];
    const float* wrow = wtile + lane*193;
    float a0[3], a1[3];
    {
        const float4* af4 = (const float4*)(af + (size_t)p*8);
        float4 t0 = af4[0], t1 = af4[1];
        a0[0] = t0.x; a0[1] = t0.y; a0[2] = t0.z;
        a1[0] = t0.w; a1[1] = t1.x; a1[2] = t1.y;
    }
    // o1: u in [16*part, 16*part+16)
    {
        int U0 = 16*wid;
        float fsr[16];
        {
            const float4* f4 = (const float4*)(fs + (size_t)s*64 + U0);
            #pragma unroll
            for (int g = 0; g < 4; ++g) {
                float4 t = f4[g];
                fsr[4*g+0] = t.x; fsr[4*g+1] = t.y; fsr[4*g+2] = t.z; fsr[4*g+3] = t.w;
            }
        }
        #pragma unroll
        for (int uu = 0; uu < 16; ++uu) {
            int u = U0 + uu;
            float su = fsr[uu]*0.125f;   // 1/sqrt(2) * 1/sqrt(32)
            float wa = wrow[2*u]   + b3[2*u];
            float wb = wrow[2*u+1] + b3[2*u+1];
            ebuf[(size_t)(u*3+0)*NEP + p] = f2b(su*(wa*a0[0] + wb*a1[0]));
            ebuf[(size_t)(u*3+1)*NEP + p] = f2b(su*(wa*a0[1] + wb*a1[1]));
            ebuf[(size_t)(u*3+2)*NEP + p] = f2b(su*(wa*a0[2] + wb*a1[2]));
        }
    }
    // o2 + o3: u in [4*part, 4*part+4)
    {
        int U0 = 4*wid;
        float fvr[12];
        {
            const float4* f4 = (const float4*)(fvv + (size_t)s*48 + 3*U0);
            #pragma unroll
            for (int g = 0; g < 3; ++g) {
                float4 t = f4[g];
                fvr[4*g+0] = t.x; fvr[4*g+1] = t.y; fvr[4*g+2] = t.z; fvr[4*g+3] = t.w;
            }
        }
        #pragma unroll
        for (int uu = 0; uu < 4; ++uu) {
            int u = U0 + uu;
            float v0 = fvr[uu*3+0], v1 = fvr[uu*3+1], v2 = fvr[uu*3+2];
            float w2a = wrow[128+2*u] + b3[128+2*u];
            float w2b = wrow[129+2*u] + b3[129+2*u];
            float w3a = wrow[160+2*u] + b3[160+2*u];
            float w3b = wrow[161+2*u] + b3[161+2*u];
            float dd0 = v0*a0[0] + v1*a0[1] + v2*a0[2];
            float dd1 = v0*a1[0] + v1*a1[1] + v2*a1[2];
            ebuf[(size_t)(192+u)*NEP + p] = f2b((w2a*dd0 + w2b*dd1)*0.07216878364870323f); // 1/sqrt(192)
            float c0x = v1*a0[2]-v2*a0[1], c0y = v2*a0[0]-v0*a0[2], c0z = v0*a0[1]-v1*a0[0];
            float c1x = v1*a1[2]-v2*a1[1], c1y = v2*a1[0]-v0*a1[2], c1z = v0*a1[1]-v1*a1[0];
            ebuf[(size_t)(208+u*3+0)*NEP + p] = f2b(0.08838834764831845f*(w3a*c0x + w3b*c1x)); // 1/sqrt(128)
            ebuf[(size_t)(208+u*3+1)*NEP + p] = f2b(0.08838834764831845f*(w3a*c0y + w3b*c1y));
            ebuf[(size_t)(208+u*3+2)*NEP + p] = f2b(0.08838834764831845f*(w3a*c0z + w3b*c1z));
        }
    }
}

// ---------------- segment-sum: ebuf rows -> mid[n][256]  (BW-shaped) ----------------
// block = 16 consecutive nodes, thread = component row; each thread scans its row
// contiguously over the 16-node edge range with 16B vector loads.
__global__ __launch_bounds__(256) void segsum_kernel(
    const unsigned short* __restrict__ ebuf,
    const int* __restrict__ segoff,
    float* __restrict__ mid)
{
    __shared__ int sbnd[17];
    int c = threadIdx.x;
    int n0 = blockIdx.x * 16;
    if (c < 17) sbnd[c] = segoff[n0 + c];
    __syncthreads();
    const unsigned short* row = ebuf + (size_t)c * NEP;
    int P1 = sbnd[16];
    int p = sbnd[0];
    float cur = 0.f;
    int seg = 0;
    int bnext = sbnd[1];
    // flush helper semantics: only called while p < P1, so seg+1 <= 16 stays in range
    #define FLUSH() { mid[(size_t)(n0 + seg)*256 + c] = cur; cur = 0.f; ++seg; bnext = sbnd[seg + 1]; }
    // scalar head to 16B alignment
    while (p < P1 && (p & 7)) {
        while (p >= bnext) FLUSH();
        cur += b2f(row[p]); ++p;
    }
    if (p < P1) { while (p >= bnext) FLUSH(); }
    // vector body
    for (; p + 8 <= P1; p += 8) {
        ushort8x v = *(const ushort8x*)(row + p);
        if (p + 8 <= bnext) {
            cur += (b2f(v[0]) + b2f(v[1])) + (b2f(v[2]) + b2f(v[3]))
                 + (b2f(v[4]) + b2f(v[5])) + (b2f(v[6]) + b2f(v[7]));
        } else {
            #pragma unroll
            for (int j = 0; j < 8; ++j) {
                while (p + j >= bnext) FLUSH();
                cur += b2f(v[j]);
            }
        }
    }
    // scalar tail
    for (; p < P1; ++p) {
        while (p >= bnext) FLUSH();
        cur += b2f(row[p]);
    }
    #undef FLUSH
    while (seg < 16) { mid[(size_t)(n0 + seg)*256 + c] = cur; cur = 0.f; ++seg; }
}

// ---------------- node update (256 threads) ----------------
__global__ __launch_bounds__(256) void node_update_kernel(
    const float* __restrict__ ys, const float* __restrict__ yv,
    float* __restrict__ ys_old, float* __restrict__ yv_old,
    const float* __restrict__ mid,
    const int* __restrict__ types,
    const float* __restrict__ scsT, const float* __restrict__ scvT,
    const float* __restrict__ lin2sT, const float* __restrict__ lin2vT,
    const float* __restrict__ siWsT, const float* __restrict__ siWvT,
    const float* __restrict__ Kbuf,
    const float* __restrict__ hv, const float* __restrict__ mixv, int layer,
    float* __restrict__ xpad, float* __restrict__ dout)
{
    int n = blockIdx.x;
    int lane = threadIdx.x;
    __shared__ float ys_l[64], yv_l[48], mids[16], midv[240];
    __shared__ float conv_s[80], conv_v[48], sis_l[64], siv_l[48], yvn[48];
    int t = types[n];
    {
        float v = mid[(size_t)n*256 + lane];
        if (lane < 192) midv[lane] = v;
        else if (lane < 208) mids[lane-192] = v;
        else midv[192 + (lane-208)] = v;
    }
    if (lane < 64) ys_l[lane] = ys[n*64 + lane];
    else if (lane < 112) yv_l[lane-64] = yv[n*48 + (lane-64)];
    __syncthreads();
    if (lane < 80) {
        const float* Wsc = scsT + (size_t)t*5120;
        const float* W2s = lin2sT + (size_t)t*1280;
        float a_sc = 0.f, a_2 = 0.f;
        #pragma unroll
        for (int i = 0; i < 64; ++i) a_sc += ys_l[i]*Wsc[i*80 + lane];
        #pragma unroll
        for (int i = 0; i < 16; ++i) a_2 += mids[i]*W2s[i*80 + lane];
        conv_s[lane] = 0.3826834323650898f*a_sc + 0.9238795325112867f*a_2;
    } else if (lane < 144) {
        int o = lane - 80;
        float a_si = 0.f;
        #pragma unroll
        for (int i = 0; i < 64; ++i) a_si += ys_l[i]*siWsT[i*64 + o];
        sis_l[o] = a_si;
    } else if (lane < 192) {
        int j = lane - 144, o = j/3, m = j%3;
        const float* Wsc = scvT + (size_t)t*256;
        const float* W2v = lin2vT + (size_t)t*1280;
        float a_sc = 0.f, a_2 = 0.f, a_si = 0.f;
        #pragma unroll
        for (int i = 0; i < 16; ++i) {
            float y = yv_l[i*3+m];
            a_sc += y*Wsc[i*16+o];
            a_si += y*siWvT[i*16+o];
        }
        #pragma unroll
        for (int i = 0; i < 80; ++i) a_2 += midv[i*3+m]*W2v[i*16+o];
        conv_v[j] = 0.3826834323650898f*a_sc + 0.9238795325112867f*a_2;
        siv_l[j] = a_si;
    }
    __syncthreads();
    float hh = hv[layer]; float h2c = hh*hh; float mx = mixv[layer];
    if (lane < 64) {
        float cs = conv_s[lane];
        float gns = cs/(1.f + __expf(-cs));
        float ns = 2.f*ys_l[lane] - ys_old[n*64+lane] + h2c*(mx*gns + (mx-1.f)*sis_l[lane]);
        ys_old[n*64+lane] = ns;
    } else if (lane >= 64 && lane < 112) {
        int j = lane-64, o = j/3;
        float g = 1.f/(1.f + __expf(-conv_s[64+o]));
        float gnv = g*conv_v[j];
        float nv = 2.f*yv_l[j] - yv_old[n*48+j] + h2c*(mx*gnv + (mx-1.f)*siv_l[j]);
        yv_old[n*48+j] = nv;
        yvn[j] = nv;
    }
    __syncthreads();
    if (lane < 6) {
        int i = lane/3, m = lane%3;
        float acc = 0.f;
        #pragma unroll
        for (int u = 0; u < 16; ++u) acc += Kbuf[2*u+i]*yvn[u*3+m];
        xpad[n*8 + lane] = acc;
        if (dout) dout[n*6 + lane] = acc;
    }
}

// ---------------- host ----------------
extern "C" void kernel_launch(void* const* d_in, const int* in_sizes, int n_in,
                              void* d_out, int out_size, void* d_ws, size_t ws_size,
                              hipStream_t stream)
{
    const float* x_in   = (const float*)d_in[0];
    const int*   types  = (const int*)  d_in[2];
    const int*   esrc   = (const int*)  d_in[3];
    const int*   edst   = (const int*)  d_in[4];
    const float* emb    = (const float*)d_in[5];
    const float* PU     = (const float*)d_in[6];
    const float* hv     = (const float*)d_in[7];
    const float* mixv   = (const float*)d_in[8];
    const float* si_Ws  = (const float*)d_in[9];
    const float* si_Wv  = (const float*)d_in[10];
    const float* sc_Ws  = (const float*)d_in[11];
    const float* sc_Wv  = (const float*)d_in[12];
    const float* lin1_Ws= (const float*)d_in[13];
    const float* lin1_Wv= (const float*)d_in[14];
    const float* lin2_Ws= (const float*)d_in[15];
    const float* lin2_Wv= (const float*)d_in[16];
    const float* fc_W1  = (const float*)d_in[17];
    const float* fc_b1  = (const float*)d_in[18];
    const float* fc_W2  = (const float*)d_in[19];
    const float* fc_b2  = (const float*)d_in[20];
    const float* fc_W3  = (const float*)d_in[21];
    const float* fc_b3  = (const float*)d_in[22];

    float* ws = (float*)d_ws;
    size_t off = 0;
    auto alloc = [&](size_t nf) { float* p = ws + off; off += nf; return p; };
    float* Kbuf   = alloc(64);
    float* x_pad  = alloc(80000);
    float* ys0    = alloc(640000);
    float* ys1    = alloc(640000);
    float* yv0    = alloc(480000);
    float* yv1    = alloc(480000);
    float* fsb    = alloc(640000);
    float* fvvb   = alloc(480000);
    float* afb    = alloc((size_t)NE*8);
    float* midb   = alloc((size_t)NN*256);
    float* lin1sT = alloc((size_t)4*100*4096);
    float* lin1vT = alloc((size_t)4*100*256);
    float* scsT   = alloc((size_t)4*100*5120);
    float* scvT   = alloc((size_t)4*100*256);
    float* lin2sT = alloc((size_t)4*100*1280);
    float* lin2vT = alloc((size_t)4*100*1280);
    float* siWsT  = alloc((size_t)4*4096);
    float* siWvT  = alloc((size_t)4*256);
    float* W1T    = alloc((size_t)4*1024);
    float* W2T    = alloc((size_t)4*4096);
    float* W3T    = alloc((size_t)4*12288);
    // int region
    int* iws = (int*)(ws + off);
    size_t ioff = 0;
    auto ialloc = [&](size_t ni) { int* p = iws + ioff; ioff += ni; return p; };
    int* deg    = ialloc(NN);
    int* segoff = ialloc(NN + 8);   // padded to keep downstream 16B alignment
    int* cursor = ialloc(NN);
    int* srcs   = ialloc(NE);
    int* dsts   = ialloc(NE);
    // bf16 region (16B-aligned)
    unsigned short* h2bf = (unsigned short*)(iws + ioff);   // [E][64]
    unsigned short* w3bf = h2bf + (size_t)NE*64;            // [L][192][64]
    unsigned short* ebuf = w3bf + (size_t)4*192*64;         // [256][NEP]

    // K + state init
    k_newton_kernel<<<1, 1, 0, stream>>>(PU, Kbuf);
    init_xpad_kernel<<<(NN*8 + 255)/256, 256, 0, stream>>>(x_in, x_pad);
    hipMemsetAsync(ys0, 0, 640000*sizeof(float), stream);
    hipMemsetAsync(ys1, 0, 640000*sizeof(float), stream);
    init_yv_kernel<<<(NN*48 + 255)/256, 256, 0, stream>>>(x_in, Kbuf, yv0, yv1);

    const float s2048 = 0.022097086912079608f;
    const float s512  = 0.044194173824159216f;
    const float s2560 = 0.019764235376052372f;
    {
        int tot;
        tot = 4*100*64*64; build_eff_kernel<<<(tot+255)/256,256,0,stream>>>(lin1_Ws, emb, lin1sT, 64, 64, s2048, tot);
        tot = 4*100*16*16; build_eff_kernel<<<(tot+255)/256,256,0,stream>>>(lin1_Wv, emb, lin1vT, 16, 16, s512,  tot);
        tot = 4*100*64*80; build_eff_kernel<<<(tot+255)/256,256,0,stream>>>(sc_Ws,   emb, scsT,   80, 64, s2048, tot);
        tot = 4*100*16*16; build_eff_kernel<<<(tot+255)/256,256,0,stream>>>(sc_Wv,   emb, scvT,   16, 16, s512,  tot);
        tot = 4*100*16*80; build_eff_kernel<<<(tot+255)/256,256,0,stream>>>(lin2_Ws, emb, lin2sT, 80, 16, s512,  tot);
        tot = 4*100*80*16; build_eff_kernel<<<(tot+255)/256,256,0,stream>>>(lin2_Wv, emb, lin2vT, 16, 80, s2560, tot);
        tot = 4*64*64;  transpose_kernel<<<(tot+255)/256,256,0,stream>>>(si_Ws, siWsT, 64, 64, 0.125f, tot);
        tot = 4*16*16;  transpose_kernel<<<(tot+255)/256,256,0,stream>>>(si_Wv, siWvT, 16, 16, 0.25f,  tot);
        tot = 4*16*64;  transpose_kernel<<<(tot+255)/256,256,0,stream>>>(fc_W1, W1T, 16, 64, 1.0f, tot);
        tot = 4*64*64;  transpose_kernel<<<(tot+255)/256,256,0,stream>>>(fc_W2, W2T, 64, 64, 1.0f, tot);
        tot = 4*64*192; transpose_kernel<<<(tot+255)/256,256,0,stream>>>(fc_W3, W3T, 64, 192, 1.0f, tot);
        tot = 4*192*64; cast_bf16_kernel<<<(tot+255)/256,256,0,stream>>>(W3T, w3bf, tot);
    }

    // counting sort by dst
    hipMemsetAsync(deg, 0, NN*sizeof(int), stream);
    hist_kernel<<<(NE+255)/256, 256, 0, stream>>>(edst, deg);
    scan_kernel<<<1, 256, 0, stream>>>(deg, segoff, cursor);
    scatter_kernel<<<(NE+255)/256, 256, 0, stream>>>(esrc, edst, cursor, srcs, dsts);

    float* ys_cur = ys0; float* ys_old = ys1;
    float* yv_cur = yv0; float* yv_old = yv1;
    for (int l = 0; l < 4; ++l) {
        node_lin1_kernel<<<NN, 128, 0, stream>>>(
            ys_cur, yv_cur, types,
            lin1sT + (size_t)l*100*4096, lin1vT + (size_t)l*100*256,
            fsb, fvvb);
        edge_mlp_kernel<<<NE/256, 256, 0, stream>>>(
            x_pad, srcs, dsts,
            W1T + (size_t)l*1024, fc_b1 + (size_t)l*64,
            W2T + (size_t)l*4096, fc_b2 + (size_t)l*64,
            h2bf, afb);
        wgemm_tp_kernel<<<NE/64, 256, 0, stream>>>(
            h2bf, w3bf + (size_t)l*192*64, fc_b3 + (size_t)l*192,
            srcs, fsb, fvvb, afb, ebuf);
        segsum_kernel<<<NN/16, 256, 0, stream>>>(ebuf, segoff, midb);
        node_update_kernel<<<NN, 256, 0, stream>>>(
            ys_cur, yv_cur, ys_old, yv_old,
            midb, types,
            scsT   + (size_t)l*100*5120, scvT   + (size_t)l*100*256,
            lin2sT + (size_t)l*100*1280, lin2vT + (size_t)l*100*1280,
            siWsT  + (size_t)l*4096,     siWvT  + (size_t)l*256,
            Kbuf, hv, mixv, l, x_pad, (l == 3) ? (float*)d_out : nullptr);
        float* tmp;
        tmp = ys_cur; ys_cur = ys_old; ys_old = tmp;
        tmp = yv_cur; yv_cur = yv_old; yv_old = tmp;
    }
}

// Round 6
// 2505.828 us; speedup vs baseline: 1.0079x; 1.0079x over previous
//
#include <hip/hip_runtime.h>
#include <math.h>

#define NN 10000
#define NE 320000
#define NEP (NE + 64)      // padded ebuf row stride (breaks 1KiB channel alignment)
#define PI_F 3.14159265358979323846f

typedef __attribute__((ext_vector_type(8))) short short8x;
typedef __attribute__((ext_vector_type(8))) unsigned short ushort8x;
typedef __attribute__((ext_vector_type(4))) float float4x;

__device__ __forceinline__ unsigned short f2b(float f) {
    unsigned b = __float_as_uint(f);
    return (unsigned short)((b + 0x7FFFu + ((b >> 16) & 1u)) >> 16);
}
__device__ __forceinline__ float b2f(unsigned short u) {
    return __uint_as_float(((unsigned)u) << 16);
}
__device__ __forceinline__ float silu(float x) {
    return x / (1.f + __expf(-x));
}

// ---------------- K = Newton-Schulz semi-unitary (16x2) ----------------
__global__ void k_newton_kernel(const float* __restrict__ PU, float* __restrict__ Kout)
{
    if (threadIdx.x != 0 || blockIdx.x != 0) return;
    float K[32];
    float nrm = 0.f;
    for (int i = 0; i < 32; ++i) { K[i] = PU[i]; nrm += K[i]*K[i]; }
    float inv = 1.0f / sqrtf(nrm);
    for (int i = 0; i < 32; ++i) K[i] *= inv;
    for (int it = 0; it < 10; ++it) {
        float m00 = 0.f, m01 = 0.f, m11 = 0.f;
        for (int u = 0; u < 16; ++u) {
            float a = K[2*u], b = K[2*u+1];
            m00 += a*a; m01 += a*b; m11 += b*b;
        }
        for (int u = 0; u < 16; ++u) {
            float a = K[2*u], b = K[2*u+1];
            K[2*u]   = 1.5f*a - 0.5f*(a*m00 + b*m01);
            K[2*u+1] = 1.5f*b - 0.5f*(a*m01 + b*m11);
        }
    }
    for (int i = 0; i < 32; ++i) Kout[i] = K[i];
}

// ---------------- x_pad init: (N,6) -> (N,8) ----------------
__global__ void init_xpad_kernel(const float* __restrict__ x, float* __restrict__ xp)
{
    int tid = blockIdx.x*blockDim.x + threadIdx.x;
    if (tid >= NN*8) return;
    int n = tid >> 3, c = tid & 7;
    xp[tid] = (c < 6) ? x[n*6 + c] : 0.f;
}

// ---------------- yv init ----------------
__global__ void init_yv_kernel(const float* __restrict__ x, const float* __restrict__ K,
                               float* __restrict__ yv0, float* __restrict__ yv1)
{
    int tid = blockIdx.x*blockDim.x + threadIdx.x;
    if (tid >= NN*48) return;
    int n = tid/48, j = tid%48, u = j/3, m = j%3;
    float v = K[2*u]*x[n*6+m] + K[2*u+1]*x[n*6+3+m];
    yv0[tid] = v; yv1[tid] = v;
}

// ---------------- per-type effective weights ----------------
__global__ void build_eff_kernel(const float* __restrict__ W, const float* __restrict__ emb,
                                 float* __restrict__ out, int O, int I, float scale, int total)
{
    int tid = blockIdx.x*blockDim.x + threadIdx.x;
    if (tid >= total) return;
    int o = tid % O; int r = tid / O;
    int i = r % I; r /= I;
    int t = r % 100; int l = r / 100;
    const float* w  = W + (((size_t)l*O + o)*I + i)*32;
    const float* em = emb + (size_t)t*32;
    float acc = 0.f;
    #pragma unroll
    for (int e = 0; e < 32; ++e) acc += w[e]*em[e];
    out[tid] = acc*scale;
}

// ---------------- transpose (L,O,I) -> (L,I,O), scaled ----------------
__global__ void transpose_kernel(const float* __restrict__ W, float* __restrict__ out,
                                 int O, int I, float scale, int total)
{
    int tid = blockIdx.x*blockDim.x + threadIdx.x;
    if (tid >= total) return;
    int o = tid % O; int r = tid / O;
    int i = r % I; int l = r / I;
    out[tid] = W[((size_t)l*O + o)*I + i]*scale;
}

// ---------------- f32 -> bf16 cast ----------------
__global__ void cast_bf16_kernel(const float* __restrict__ in, unsigned short* __restrict__ out, int total)
{
    int tid = blockIdx.x*blockDim.x + threadIdx.x;
    if (tid < total) out[tid] = f2b(in[tid]);
}

// ---------------- pack MLP weight [L][K][N] -> bf16 [L][N][KP] (zero-pad K->KP) ----------------
__global__ void pack_w_kernel(const float* __restrict__ W, unsigned short* __restrict__ out,
                              int K, int N, int KP, int total)
{
    int tid = blockIdx.x*blockDim.x + threadIdx.x;
    if (tid >= total) return;
    int kk = tid % KP; int r = tid / KP;
    int n = r % N; int l = r / N;
    float v = (kk < K) ? W[((size_t)l*K + kk)*N + n] : 0.f;
    out[tid] = f2b(v);
}

// ---------------- counting sort by dst ----------------
__global__ void hist_kernel(const int* __restrict__ dst, int* __restrict__ deg)
{
    int e = blockIdx.x*256 + threadIdx.x;
    if (e < NE) atomicAdd(&deg[dst[e]], 1);
}

__global__ __launch_bounds__(256) void scan_kernel(const int* __restrict__ deg,
                                                   int* __restrict__ segoff,
                                                   int* __restrict__ cursor)
{
    __shared__ int part[256];
    int tid = threadIdx.x;
    int base = tid*40;
    int s = 0;
    for (int i = 0; i < 40; ++i) { int idx = base+i; if (idx < NN) s += deg[idx]; }
    part[tid] = s;
    __syncthreads();
    for (int o = 1; o < 256; o <<= 1) {
        int v = (tid >= o) ? part[tid-o] : 0;
        __syncthreads();
        part[tid] += v;
        __syncthreads();
    }
    int excl = part[tid] - s;
    for (int i = 0; i < 40; ++i) {
        int idx = base+i;
        if (idx < NN) { segoff[idx] = excl; cursor[idx] = excl; excl += deg[idx]; }
        else if (idx == NN) { segoff[NN] = excl; }
    }
}

__global__ void scatter_kernel(const int* __restrict__ src, const int* __restrict__ dst,
                               int* __restrict__ cursor,
                               int* __restrict__ srcs, int* __restrict__ dsts)
{
    int e = blockIdx.x*256 + threadIdx.x;
    if (e >= NE) return;
    int d = dst[e];
    int p = atomicAdd(&cursor[d], 1);
    srcs[p] = src[e]; dsts[p] = d;
}

// ---------------- lin1 FCTP ----------------
__global__ __launch_bounds__(128) void node_lin1_kernel(
    const float* __restrict__ ys, const float* __restrict__ yv,
    const int* __restrict__ types,
    const float* __restrict__ lin1sT, const float* __restrict__ lin1vT,
    float* __restrict__ fs, float* __restrict__ fvv)
{
    int n = blockIdx.x;
    int lane = threadIdx.x;
    __shared__ float ys_l[64];
    __shared__ float yv_l[48];
    int t = types[n];
    if (lane < 64) ys_l[lane] = ys[n*64 + lane];
    else if (lane < 112) yv_l[lane-64] = yv[n*48 + (lane-64)];
    __syncthreads();
    if (lane < 64) {
        const float* W = lin1sT + (size_t)t*4096;
        float acc = 0.f;
        #pragma unroll
        for (int i = 0; i < 64; ++i) acc += ys_l[i]*W[i*64 + lane];
        fs[n*64 + lane] = acc;
    } else if (lane < 112) {
        int j = lane - 64, o = j/3, m = j%3;
        const float* W = lin1vT + (size_t)t*256;
        float acc = 0.f;
        #pragma unroll
        for (int i = 0; i < 16; ++i) acc += yv_l[i*3+m]*W[i*16 + o];
        fvv[n*48 + j] = acc;
    }
}

// ---------------- fused edge kernel: geometry -> MFMA MLP chain -> TP -> ebuf ----------------
// block = 256 threads = 4 waves = 64 edges. Wave w owns edges [16w,16w+16) for GEMMs.
// hbuf [64][72] bf16: per-wave-exclusive rows; holds ef (K=32, zero-padded), then h1, then h2.
// wtile [64][193] f32: raw w = h2 @ W3 (bias added in TP).
// ebuf component-major [256][NEP] bf16 (o1: [0,192), o2: [192,208), o3: [208,256)).
__global__ __launch_bounds__(256) void edge_fused_kernel(
    const float* __restrict__ xp,
    const int* __restrict__ srcs, const int* __restrict__ dsts,
    const unsigned short* __restrict__ w1b,   // [64 n][32 k] bf16 (k 16..31 zero)
    const float* __restrict__ b1,
    const unsigned short* __restrict__ w2b,   // [64 n][64 k] bf16
    const float* __restrict__ b2,
    const unsigned short* __restrict__ w3b,   // [192 n][64 k] bf16
    const float* __restrict__ b3,
    const float* __restrict__ fs, const float* __restrict__ fvv,
    unsigned short* __restrict__ ebuf)
{
    __shared__ float wtile[64*193];
    __shared__ unsigned short hbuf[64*72];
    __shared__ float abuf[64*6];
    int lane = threadIdx.x & 63;
    int wid  = threadIdx.x >> 6;
    int eblk = blockIdx.x * 64;
    int row16 = lane & 15, quad = lane >> 4;
    int erow = 16*wid + row16;

    // ---- phase G: lanes 0..15 of each wave: geometry for edge eblk+16w+lane ----
    if (lane < 16) {
        int p = eblk + 16*wid + lane;
        int s = srcs[p], d = dsts[p];
        const float4* xs4 = (const float4*)(xp + (size_t)s*8);
        const float4* xd4 = (const float4*)(xp + (size_t)d*8);
        float4 xsa = xs4[0], xsb = xs4[1];
        float4 xda = xd4[0], xdb = xd4[1];
        float a0[3], a1[3], ef[16];
        {
            float d0 = xsa.x-xda.x, d1 = xsa.y-xda.y, d2 = xsa.z-xda.z;
            float r = sqrtf(d0*d0 + d1*d1 + d2*d2);
            float invr = 1.0f/r;
            float u = 0.8f*r - 2.0f;
            float cut = (u > 0.f) ? 0.f : ((u < -1.f) ? 1.f : 0.5f*(1.f - __cosf(PI_F*u)));
            float sc = 1.7320508075688772f*cut*invr;
            a0[0] = sc*d0; a0[1] = sc*d1; a0[2] = sc*d2;
            float fsc = 2.5298221281347035f*invr;
            #pragma unroll
            for (int k = 0; k < 8; ++k) ef[k] = fsc*__sinf((k+1)*1.2566370614359172f*r);
        }
        {
            float d0 = xsa.w-xda.w, d1 = xsb.x-xdb.x, d2 = xsb.y-xdb.y;
            float r = sqrtf(d0*d0 + d1*d1 + d2*d2);
            float invr = 1.0f/r;
            float u = 0.8f*r - 2.0f;
            float cut = (u > 0.f) ? 0.f : ((u < -1.f) ? 1.f : 0.5f*(1.f - __cosf(PI_F*u)));
            float sc = 1.7320508075688772f*cut*invr;
            a1[0] = sc*d0; a1[1] = sc*d1; a1[2] = sc*d2;
            float fsc = 2.5298221281347035f*invr;
            #pragma unroll
            for (int k = 0; k < 8; ++k) ef[8+k] = fsc*__sinf((k+1)*1.2566370614359172f*r);
        }
        float* ab = abuf + (16*wid + lane)*6;
        ab[0] = a0[0]; ab[1] = a0[1]; ab[2] = a0[2];
        ab[3] = a1[0]; ab[4] = a1[1]; ab[5] = a1[2];
        // pack ef -> bf16 row [0..15], zeros [16..31]
        unsigned epk[8];
        #pragma unroll
        for (int k = 0; k < 8; ++k)
            epk[k] = (unsigned)f2b(ef[2*k]) | ((unsigned)f2b(ef[2*k+1]) << 16);
        uint4* hr = (uint4*)(hbuf + (16*wid + lane)*72);
        uint4 q0; q0.x = epk[0]; q0.y = epk[1]; q0.z = epk[2]; q0.w = epk[3];
        uint4 q1; q1.x = epk[4]; q1.y = epk[5]; q1.z = epk[6]; q1.w = epk[7];
        uint4 qz; qz.x = 0; qz.y = 0; qz.z = 0; qz.w = 0;
        hr[0] = q0; hr[1] = q1; hr[2] = qz; hr[3] = qz;
    }
    // no __syncthreads needed: hbuf rows are wave-exclusive, DS ops retire in order per wave

    // ---- GEMM1: h1 = silu(ef @ W1 + b1), K=32 (one step) ----
    {
        short8x a = *(const short8x*)(hbuf + erow*72 + quad*8);
        float4x c[4];
        #pragma unroll
        for (int nt = 0; nt < 4; ++nt) {
            short8x b = *(const short8x*)(w1b + ((size_t)(nt*16 + row16))*32 + quad*8);
            c[nt] = __builtin_amdgcn_mfma_f32_16x16x32_bf16(a, b, (float4x){0.f,0.f,0.f,0.f}, 0, 0, 0);
        }
        #pragma unroll
        for (int nt = 0; nt < 4; ++nt) {
            float bias = b1[nt*16 + row16];
            #pragma unroll
            for (int r = 0; r < 4; ++r) {
                float h = silu(c[nt][r] + bias);
                hbuf[(16*wid + quad*4 + r)*72 + nt*16 + row16] = f2b(h);
            }
        }
    }
    // ---- GEMM2: h2 = silu(h1 @ W2 + b2), K=64 (two steps) ----
    {
        short8x a0v = *(const short8x*)(hbuf + erow*72 + 0*32 + quad*8);
        short8x a1v = *(const short8x*)(hbuf + erow*72 + 1*32 + quad*8);
        float4x c[4];
        #pragma unroll
        for (int nt = 0; nt < 4; ++nt) {
            short8x b0 = *(const short8x*)(w2b + ((size_t)(nt*16 + row16))*64 + 0*32 + quad*8);
            float4x t = __builtin_amdgcn_mfma_f32_16x16x32_bf16(a0v, b0, (float4x){0.f,0.f,0.f,0.f}, 0, 0, 0);
            short8x b1v = *(const short8x*)(w2b + ((size_t)(nt*16 + row16))*64 + 1*32 + quad*8);
            c[nt] = __builtin_amdgcn_mfma_f32_16x16x32_bf16(a1v, b1v, t, 0, 0, 0);
        }
        #pragma unroll
        for (int nt = 0; nt < 4; ++nt) {
            float bias = b2[nt*16 + row16];
            #pragma unroll
            for (int r = 0; r < 4; ++r) {
                float h = silu(c[nt][r] + bias);
                hbuf[(16*wid + quad*4 + r)*72 + nt*16 + row16] = f2b(h);
            }
        }
    }
    // ---- GEMM3: w = h2 @ W3 (raw, bias later), 12 N-tiles x 2 K-steps ----
    {
        short8x a0v = *(const short8x*)(hbuf + erow*72 + 0*32 + quad*8);
        short8x a1v = *(const short8x*)(hbuf + erow*72 + 1*32 + quad*8);
        float4x acc[12];
        #pragma unroll
        for (int nt = 0; nt < 12; ++nt) {
            short8x b0 = *(const short8x*)(w3b + ((size_t)(nt*16 + row16))*64 + 0*32 + quad*8);
            float4x t = __builtin_amdgcn_mfma_f32_16x16x32_bf16(a0v, b0, (float4x){0.f,0.f,0.f,0.f}, 0, 0, 0);
            short8x b1v = *(const short8x*)(w3b + ((size_t)(nt*16 + row16))*64 + 1*32 + quad*8);
            acc[nt] = __builtin_amdgcn_mfma_f32_16x16x32_bf16(a1v, b1v, t, 0, 0, 0);
        }
        #pragma unroll
        for (int nt = 0; nt < 12; ++nt) {
            #pragma unroll
            for (int r = 0; r < 4; ++r) {
                wtile[(16*wid + quad*4 + r)*193 + nt*16 + row16] = acc[nt][r];
            }
        }
    }
    __syncthreads();

    // ---- TP phase: thread (edge = lane, part = wid) ----
    int p = eblk + lane;
    const float* wrow = wtile + lane*193;
    float a0[3], a1[3];
    {
        const float* ab = abuf + lane*6;
        a0[0] = ab[0]; a0[1] = ab[1]; a0[2] = ab[2];
        a1[0] = ab[3]; a1[1] = ab[4]; a1[2] = ab[5];
    }
    int s = srcs[p];
    // o1: u in [16*part, 16*part+16)
    {
        int U0 = 16*wid;
        float fsr[16];
        {
            const float4* f4 = (const float4*)(fs + (size_t)s*64 + U0);
            #pragma unroll
            for (int g = 0; g < 4; ++g) {
                float4 t = f4[g];
                fsr[4*g+0] = t.x; fsr[4*g+1] = t.y; fsr[4*g+2] = t.z; fsr[4*g+3] = t.w;
            }
        }
        #pragma unroll
        for (int uu = 0; uu < 16; ++uu) {
            int u = U0 + uu;
            float su = fsr[uu]*0.125f;   // 1/sqrt(2) * 1/sqrt(32)
            float wa = wrow[2*u]   + b3[2*u];
            float wb = wrow[2*u+1] + b3[2*u+1];
            ebuf[(size_t)(u*3+0)*NEP + p] = f2b(su*(wa*a0[0] + wb*a1[0]));
            ebuf[(size_t)(u*3+1)*NEP + p] = f2b(su*(wa*a0[1] + wb*a1[1]));
            ebuf[(size_t)(u*3+2)*NEP + p] = f2b(su*(wa*a0[2] + wb*a1[2]));
        }
    }
    // o2 + o3: u in [4*part, 4*part+4)
    {
        int U0 = 4*wid;
        float fvr[12];
        {
            const float4* f4 = (const float4*)(fvv + (size_t)s*48 + 3*U0);
            #pragma unroll
            for (int g = 0; g < 3; ++g) {
                float4 t = f4[g];
                fvr[4*g+0] = t.x; fvr[4*g+1] = t.y; fvr[4*g+2] = t.z; fvr[4*g+3] = t.w;
            }
        }
        #pragma unroll
        for (int uu = 0; uu < 4; ++uu) {
            int u = U0 + uu;
            float v0 = fvr[uu*3+0], v1 = fvr[uu*3+1], v2 = fvr[uu*3+2];
            float w2a = wrow[128+2*u] + b3[128+2*u];
            float w2b = wrow[129+2*u] + b3[129+2*u];
            float w3a = wrow[160+2*u] + b3[160+2*u];
            float w3b = wrow[161+2*u] + b3[161+2*u];
            float dd0 = v0*a0[0] + v1*a0[1] + v2*a0[2];
            float dd1 = v0*a1[0] + v1*a1[1] + v2*a1[2];
            ebuf[(size_t)(192+u)*NEP + p] = f2b((w2a*dd0 + w2b*dd1)*0.07216878364870323f); // 1/sqrt(192)
            float c0x = v1*a0[2]-v2*a0[1], c0y = v2*a0[0]-v0*a0[2], c0z = v0*a0[1]-v1*a0[0];
            float c1x = v1*a1[2]-v2*a1[1], c1y = v2*a1[0]-v0*a1[2], c1z = v0*a1[1]-v1*a1[0];
            ebuf[(size_t)(208+u*3+0)*NEP + p] = f2b(0.08838834764831845f*(w3a*c0x + w3b*c1x)); // 1/sqrt(128)
            ebuf[(size_t)(208+u*3+1)*NEP + p] = f2b(0.08838834764831845f*(w3a*c0y + w3b*c1y));
            ebuf[(size_t)(208+u*3+2)*NEP + p] = f2b(0.08838834764831845f*(w3a*c0z + w3b*c1z));
        }
    }
}

// ---------------- segment-sum: block = 4 nodes, thread = component row ----------------
__global__ __launch_bounds__(256) void segsum_kernel(
    const unsigned short* __restrict__ ebuf,
    const int* __restrict__ segoff,
    float* __restrict__ mid)
{
    __shared__ int sb[5];
    int c = threadIdx.x;
    int n0 = blockIdx.x * 4;
    if (c < 5) sb[c] = segoff[n0 + c];
    __syncthreads();
    const unsigned short* row = ebuf + (size_t)c * NEP;
    #pragma unroll 1
    for (int j = 0; j < 4; ++j) {
        int p = sb[j], p1 = sb[j+1];
        float acc = 0.f, acc2 = 0.f;
        while (p < p1 && (p & 7)) { acc += b2f(row[p]); ++p; }
        for (; p + 8 <= p1; p += 8) {
            ushort8x v = *(const ushort8x*)(row + p);
            acc  += (b2f(v[0]) + b2f(v[1])) + (b2f(v[2]) + b2f(v[3]));
            acc2 += (b2f(v[4]) + b2f(v[5])) + (b2f(v[6]) + b2f(v[7]));
        }
        for (; p < p1; ++p) acc += b2f(row[p]);
        mid[(size_t)(n0 + j)*256 + c] = acc + acc2;
    }
}

// ---------------- node update (256 threads) ----------------
__global__ __launch_bounds__(256) void node_update_kernel(
    const float* __restrict__ ys, const float* __restrict__ yv,
    float* __restrict__ ys_old, float* __restrict__ yv_old,
    const float* __restrict__ mid,
    const int* __restrict__ types,
    const float* __restrict__ scsT, const float* __restrict__ scvT,
    const float* __restrict__ lin2sT, const float* __restrict__ lin2vT,
    const float* __restrict__ siWsT, const float* __restrict__ siWvT,
    const float* __restrict__ Kbuf,
    const float* __restrict__ hv, const float* __restrict__ mixv, int layer,
    float* __restrict__ xpad, float* __restrict__ dout)
{
    int n = blockIdx.x;
    int lane = threadIdx.x;
    __shared__ float ys_l[64], yv_l[48], mids[16], midv[240];
    __shared__ float conv_s[80], conv_v[48], sis_l[64], siv_l[48], yvn[48];
    int t = types[n];
    {
        float v = mid[(size_t)n*256 + lane];
        if (lane < 192) midv[lane] = v;
        else if (lane < 208) mids[lane-192] = v;
        else midv[192 + (lane-208)] = v;
    }
    if (lane < 64) ys_l[lane] = ys[n*64 + lane];
    else if (lane < 112) yv_l[lane-64] = yv[n*48 + (lane-64)];
    __syncthreads();
    if (lane < 80) {
        const float* Wsc = scsT + (size_t)t*5120;
        const float* W2s = lin2sT + (size_t)t*1280;
        float a_sc = 0.f, a_2 = 0.f;
        #pragma unroll
        for (int i = 0; i < 64; ++i) a_sc += ys_l[i]*Wsc[i*80 + lane];
        #pragma unroll
        for (int i = 0; i < 16; ++i) a_2 += mids[i]*W2s[i*80 + lane];
        conv_s[lane] = 0.3826834323650898f*a_sc + 0.9238795325112867f*a_2;
    } else if (lane < 144) {
        int o = lane - 80;
        float a_si = 0.f;
        #pragma unroll
        for (int i = 0; i < 64; ++i) a_si += ys_l[i]*siWsT[i*64 + o];
        sis_l[o] = a_si;
    } else if (lane < 192) {
        int j = lane - 144, o = j/3, m = j%3;
        const float* Wsc = scvT + (size_t)t*256;
        const float* W2v = lin2vT + (size_t)t*1280;
        float a_sc = 0.f, a_2 = 0.f, a_si = 0.f;
        #pragma unroll
        for (int i = 0; i < 16; ++i) {
            float y = yv_l[i*3+m];
            a_sc += y*Wsc[i*16+o];
            a_si += y*siWvT[i*16+o];
        }
        #pragma unroll
        for (int i = 0; i < 80; ++i) a_2 += midv[i*3+m]*W2v[i*16+o];
        conv_v[j] = 0.3826834323650898f*a_sc + 0.9238795325112867f*a_2;
        siv_l[j] = a_si;
    }
    __syncthreads();
    float hh = hv[layer]; float h2c = hh*hh; float mx = mixv[layer];
    if (lane < 64) {
        float cs = conv_s[lane];
        float gns = cs/(1.f + __expf(-cs));
        float ns = 2.f*ys_l[lane] - ys_old[n*64+lane] + h2c*(mx*gns + (mx-1.f)*sis_l[lane]);
        ys_old[n*64+lane] = ns;
    } else if (lane >= 64 && lane < 112) {
        int j = lane-64, o = j/3;
        float g = 1.f/(1.f + __expf(-conv_s[64+o]));
        float gnv = g*conv_v[j];
        float nv = 2.f*yv_l[j] - yv_old[n*48+j] + h2c*(mx*gnv + (mx-1.f)*siv_l[j]);
        yv_old[n*48+j] = nv;
        yvn[j] = nv;
    }
    __syncthreads();
    if (lane < 6) {
        int i = lane/3, m = lane%3;
        float acc = 0.f;
        #pragma unroll
        for (int u = 0; u < 16; ++u) acc += Kbuf[2*u+i]*yvn[u*3+m];
        xpad[n*8 + lane] = acc;
        if (dout) dout[n*6 + lane] = acc;
    }
}

// ---------------- host ----------------
extern "C" void kernel_launch(void* const* d_in, const int* in_sizes, int n_in,
                              void* d_out, int out_size, void* d_ws, size_t ws_size,
                              hipStream_t stream)
{
    const float* x_in   = (const float*)d_in[0];
    const int*   types  = (const int*)  d_in[2];
    const int*   esrc   = (const int*)  d_in[3];
    const int*   edst   = (const int*)  d_in[4];
    const float* emb    = (const float*)d_in[5];
    const float* PU     = (const float*)d_in[6];
    const float* hv     = (const float*)d_in[7];
    const float* mixv   = (const float*)d_in[8];
    const float* si_Ws  = (const float*)d_in[9];
    const float* si_Wv  = (const float*)d_in[10];
    const float* sc_Ws  = (const float*)d_in[11];
    const float* sc_Wv  = (const float*)d_in[12];
    const float* lin1_Ws= (const float*)d_in[13];
    const float* lin1_Wv= (const float*)d_in[14];
    const float* lin2_Ws= (const float*)d_in[15];
    const float* lin2_Wv= (const float*)d_in[16];
    const float* fc_W1  = (const float*)d_in[17];
    const float* fc_b1  = (const float*)d_in[18];
    const float* fc_W2  = (const float*)d_in[19];
    const float* fc_b2  = (const float*)d_in[20];
    const float* fc_W3  = (const float*)d_in[21];
    const float* fc_b3  = (const float*)d_in[22];

    float* ws = (float*)d_ws;
    size_t off = 0;
    auto alloc = [&](size_t nf) { float* p = ws + off; off += nf; return p; };
    float* Kbuf   = alloc(64);
    float* x_pad  = alloc(80000);
    float* ys0    = alloc(640000);
    float* ys1    = alloc(640000);
    float* yv0    = alloc(480000);
    float* yv1    = alloc(480000);
    float* fsb    = alloc(640000);
    float* fvvb   = alloc(480000);
    float* midb   = alloc((size_t)NN*256);
    float* lin1sT = alloc((size_t)4*100*4096);
    float* lin1vT = alloc((size_t)4*100*256);
    float* scsT   = alloc((size_t)4*100*5120);
    float* scvT   = alloc((size_t)4*100*256);
    float* lin2sT = alloc((size_t)4*100*1280);
    float* lin2vT = alloc((size_t)4*100*1280);
    float* siWsT  = alloc((size_t)4*4096);
    float* siWvT  = alloc((size_t)4*256);
    float* W3T    = alloc((size_t)4*12288);
    // int region
    int* iws = (int*)(ws + off);
    size_t ioff = 0;
    auto ialloc = [&](size_t ni) { int* p = iws + ioff; ioff += ni; return p; };
    int* deg    = ialloc(NN);
    int* segoff = ialloc(NN + 8);   // padded to keep downstream 16B alignment
    int* cursor = ialloc(NN);
    int* srcs   = ialloc(NE);
    int* dsts   = ialloc(NE);
    // bf16 region (16B-aligned)
    unsigned short* w1bp = (unsigned short*)(iws + ioff);   // [L][64][32]
    unsigned short* w2bp = w1bp + (size_t)4*64*32;          // [L][64][64]
    unsigned short* w3bf = w2bp + (size_t)4*64*64;          // [L][192][64]
    unsigned short* ebuf = w3bf + (size_t)4*192*64;         // [256][NEP]

    // K + state init
    k_newton_kernel<<<1, 1, 0, stream>>>(PU, Kbuf);
    init_xpad_kernel<<<(NN*8 + 255)/256, 256, 0, stream>>>(x_in, x_pad);
    hipMemsetAsync(ys0, 0, 640000*sizeof(float), stream);
    hipMemsetAsync(ys1, 0, 640000*sizeof(float), stream);
    init_yv_kernel<<<(NN*48 + 255)/256, 256, 0, stream>>>(x_in, Kbuf, yv0, yv1);

    const float s2048 = 0.022097086912079608f;
    const float s512  = 0.044194173824159216f;
    const float s2560 = 0.019764235376052372f;
    {
        int tot;
        tot = 4*100*64*64; build_eff_kernel<<<(tot+255)/256,256,0,stream>>>(lin1_Ws, emb, lin1sT, 64, 64, s2048, tot);
        tot = 4*100*16*16; build_eff_kernel<<<(tot+255)/256,256,0,stream>>>(lin1_Wv, emb, lin1vT, 16, 16, s512,  tot);
        tot = 4*100*64*80; build_eff_kernel<<<(tot+255)/256,256,0,stream>>>(sc_Ws,   emb, scsT,   80, 64, s2048, tot);
        tot = 4*100*16*16; build_eff_kernel<<<(tot+255)/256,256,0,stream>>>(sc_Wv,   emb, scvT,   16, 16, s512,  tot);
        tot = 4*100*16*80; build_eff_kernel<<<(tot+255)/256,256,0,stream>>>(lin2_Ws, emb, lin2sT, 80, 16, s512,  tot);
        tot = 4*100*80*16; build_eff_kernel<<<(tot+255)/256,256,0,stream>>>(lin2_Wv, emb, lin2vT, 16, 80, s2560, tot);
        tot = 4*64*64;  transpose_kernel<<<(tot+255)/256,256,0,stream>>>(si_Ws, siWsT, 64, 64, 0.125f, tot);
        tot = 4*16*16;  transpose_kernel<<<(tot+255)/256,256,0,stream>>>(si_Wv, siWvT, 16, 16, 0.25f,  tot);
        tot = 4*64*192; transpose_kernel<<<(tot+255)/256,256,0,stream>>>(fc_W3, W3T, 64, 192, 1.0f, tot);
        tot = 4*192*64; cast_bf16_kernel<<<(tot+255)/256,256,0,stream>>>(W3T, w3bf, tot);
        tot = 4*64*32;  pack_w_kernel<<<(tot+255)/256,256,0,stream>>>(fc_W1, w1bp, 16, 64, 32, tot);
        tot = 4*64*64;  pack_w_kernel<<<(tot+255)/256,256,0,stream>>>(fc_W2, w2bp, 64, 64, 64, tot);
    }

    // counting sort by dst
    hipMemsetAsync(deg, 0, NN*sizeof(int), stream);
    hist_kernel<<<(NE+255)/256, 256, 0, stream>>>(edst, deg);
    scan_kernel<<<1, 256, 0, stream>>>(deg, segoff, cursor);
    scatter_kernel<<<(NE+255)/256, 256, 0, stream>>>(esrc, edst, cursor, srcs, dsts);

    float* ys_cur = ys0; float* ys_old = ys1;
    float* yv_cur = yv0; float* yv_old = yv1;
    for (int l = 0; l < 4; ++l) {
        node_lin1_kernel<<<NN, 128, 0, stream>>>(
            ys_cur, yv_cur, types,
            lin1sT + (size_t)l*100*4096, lin1vT + (size_t)l*100*256,
            fsb, fvvb);
        edge_fused_kernel<<<NE/64, 256, 0, stream>>>(
            x_pad, srcs, dsts,
            w1bp + (size_t)l*64*32,  fc_b1 + (size_t)l*64,
            w2bp + (size_t)l*64*64,  fc_b2 + (size_t)l*64,
            w3bf + (size_t)l*192*64, fc_b3 + (size_t)l*192,
            fsb, fvvb, ebuf);
        segsum_kernel<<<NN/4, 256, 0, stream>>>(ebuf, segoff, midb);
        node_update_kernel<<<NN, 256, 0, stream>>>(
            ys_cur, yv_cur, ys_old, yv_old,
            midb, types,
            scsT   + (size_t)l*100*5120, scvT   + (size_t)l*100*256,
            lin2sT + (size_t)l*100*1280, lin2vT + (size_t)l*100*1280,
            siWsT  + (size_t)l*4096,     siWvT  + (size_t)l*256,
            Kbuf, hv, mixv, l, x_pad, (l == 3) ? (float*)d_out : nullptr);
        float* tmp;
        tmp = ys_cur; ys_cur = ys_old; ys_old = tmp;
        tmp = yv_cur; yv_cur = yv_old; yv_old = tmp;
    }
}

// Round 7
// 1295.548 us; speedup vs baseline: 1.9495x; 1.9342x over previous
//
#include <hip/hip_runtime.h>
#include <math.h>

#define NN 10000
#define NE 320000
#define NEP (NE + 64)      // padded ebuf row stride
#define PI_F 3.14159265358979323846f

typedef __attribute__((ext_vector_type(8))) short short8x;
typedef __attribute__((ext_vector_type(8))) unsigned short ushort8x;
typedef __attribute__((ext_vector_type(4))) float float4x;

__device__ __forceinline__ unsigned short f2b(float f) {
    unsigned b = __float_as_uint(f);
    return (unsigned short)((b + 0x7FFFu + ((b >> 16) & 1u)) >> 16);
}
__device__ __forceinline__ float b2f(unsigned short u) {
    return __uint_as_float(((unsigned)u) << 16);
}
__device__ __forceinline__ float silu(float x) {
    return x / (1.f + __expf(-x));
}

// ---------------- K = Newton-Schulz semi-unitary (16x2) ----------------
__global__ void k_newton_kernel(const float* __restrict__ PU, float* __restrict__ Kout)
{
    if (threadIdx.x != 0 || blockIdx.x != 0) return;
    float K[32];
    float nrm = 0.f;
    for (int i = 0; i < 32; ++i) { K[i] = PU[i]; nrm += K[i]*K[i]; }
    float inv = 1.0f / sqrtf(nrm);
    for (int i = 0; i < 32; ++i) K[i] *= inv;
    for (int it = 0; it < 10; ++it) {
        float m00 = 0.f, m01 = 0.f, m11 = 0.f;
        for (int u = 0; u < 16; ++u) {
            float a = K[2*u], b = K[2*u+1];
            m00 += a*a; m01 += a*b; m11 += b*b;
        }
        for (int u = 0; u < 16; ++u) {
            float a = K[2*u], b = K[2*u+1];
            K[2*u]   = 1.5f*a - 0.5f*(a*m00 + b*m01);
            K[2*u+1] = 1.5f*b - 0.5f*(a*m01 + b*m11);
        }
    }
    for (int i = 0; i < 32; ++i) Kout[i] = K[i];
}

// ---------------- x_pad init: (N,6) -> (N,8) ----------------
__global__ void init_xpad_kernel(const float* __restrict__ x, float* __restrict__ xp)
{
    int tid = blockIdx.x*blockDim.x + threadIdx.x;
    if (tid >= NN*8) return;
    int n = tid >> 3, c = tid & 7;
    xp[tid] = (c < 6) ? x[n*6 + c] : 0.f;
}

// ---------------- yv init ----------------
__global__ void init_yv_kernel(const float* __restrict__ x, const float* __restrict__ K,
                               float* __restrict__ yv0, float* __restrict__ yv1)
{
    int tid = blockIdx.x*blockDim.x + threadIdx.x;
    if (tid >= NN*48) return;
    int n = tid/48, j = tid%48, u = j/3, m = j%3;
    float v = K[2*u]*x[n*6+m] + K[2*u+1]*x[n*6+3+m];
    yv0[tid] = v; yv1[tid] = v;
}

// ---------------- per-type effective weights ----------------
__global__ void build_eff_kernel(const float* __restrict__ W, const float* __restrict__ emb,
                                 float* __restrict__ out, int O, int I, float scale, int total)
{
    int tid = blockIdx.x*blockDim.x + threadIdx.x;
    if (tid >= total) return;
    int o = tid % O; int r = tid / O;
    int i = r % I; r /= I;
    int t = r % 100; int l = r / 100;
    const float* w  = W + (((size_t)l*O + o)*I + i)*32;
    const float* em = emb + (size_t)t*32;
    float acc = 0.f;
    #pragma unroll
    for (int e = 0; e < 32; ++e) acc += w[e]*em[e];
    out[tid] = acc*scale;
}

// ---------------- transpose (L,O,I) -> (L,I,O), scaled ----------------
__global__ void transpose_kernel(const float* __restrict__ W, float* __restrict__ out,
                                 int O, int I, float scale, int total)
{
    int tid = blockIdx.x*blockDim.x + threadIdx.x;
    if (tid >= total) return;
    int o = tid % O; int r = tid / O;
    int i = r % I; int l = r / I;
    out[tid] = W[((size_t)l*O + o)*I + i]*scale;
}

// ---------------- f32 -> bf16 cast ----------------
__global__ void cast_bf16_kernel(const float* __restrict__ in, unsigned short* __restrict__ out, int total)
{
    int tid = blockIdx.x*blockDim.x + threadIdx.x;
    if (tid < total) out[tid] = f2b(in[tid]);
}

// ---------------- pack MLP weight [L][K][N] -> bf16 [L][N][KP] (zero-pad K->KP) ----------------
__global__ void pack_w_kernel(const float* __restrict__ W, unsigned short* __restrict__ out,
                              int K, int N, int KP, int total)
{
    int tid = blockIdx.x*blockDim.x + threadIdx.x;
    if (tid >= total) return;
    int kk = tid % KP; int r = tid / KP;
    int n = r % N; int l = r / N;
    float v = (kk < K) ? W[((size_t)l*K + kk)*N + n] : 0.f;
    out[tid] = f2b(v);
}

// ---------------- counting sort by dst ----------------
__global__ void hist_kernel(const int* __restrict__ dst, int* __restrict__ deg)
{
    int e = blockIdx.x*256 + threadIdx.x;
    if (e < NE) atomicAdd(&deg[dst[e]], 1);
}

__global__ __launch_bounds__(256) void scan_kernel(const int* __restrict__ deg,
                                                   int* __restrict__ segoff,
                                                   int* __restrict__ cursor)
{
    __shared__ int part[256];
    int tid = threadIdx.x;
    int base = tid*40;
    int s = 0;
    for (int i = 0; i < 40; ++i) { int idx = base+i; if (idx < NN) s += deg[idx]; }
    part[tid] = s;
    __syncthreads();
    for (int o = 1; o < 256; o <<= 1) {
        int v = (tid >= o) ? part[tid-o] : 0;
        __syncthreads();
        part[tid] += v;
        __syncthreads();
    }
    int excl = part[tid] - s;
    for (int i = 0; i < 40; ++i) {
        int idx = base+i;
        if (idx < NN) { segoff[idx] = excl; cursor[idx] = excl; excl += deg[idx]; }
        else if (idx == NN) { segoff[NN] = excl; }
    }
}

__global__ void scatter_kernel(const int* __restrict__ src, const int* __restrict__ dst,
                               int* __restrict__ cursor,
                               int* __restrict__ srcs, int* __restrict__ dsts)
{
    int e = blockIdx.x*256 + threadIdx.x;
    if (e >= NE) return;
    int d = dst[e];
    int p = atomicAdd(&cursor[d], 1);
    srcs[p] = src[e]; dsts[p] = d;
}

// ---------------- lin1 FCTP ----------------
__global__ __launch_bounds__(128) void node_lin1_kernel(
    const float* __restrict__ ys, const float* __restrict__ yv,
    const int* __restrict__ types,
    const float* __restrict__ lin1sT, const float* __restrict__ lin1vT,
    float* __restrict__ fs, float* __restrict__ fvv)
{
    int n = blockIdx.x;
    int lane = threadIdx.x;
    __shared__ float ys_l[64];
    __shared__ float yv_l[48];
    int t = types[n];
    if (lane < 64) ys_l[lane] = ys[n*64 + lane];
    else if (lane < 112) yv_l[lane-64] = yv[n*48 + (lane-64)];
    __syncthreads();
    if (lane < 64) {
        const float* W = lin1sT + (size_t)t*4096;
        float acc = 0.f;
        #pragma unroll
        for (int i = 0; i < 64; ++i) acc += ys_l[i]*W[i*64 + lane];
        fs[n*64 + lane] = acc;
    } else if (lane < 112) {
        int j = lane - 64, o = j/3, m = j%3;
        const float* W = lin1vT + (size_t)t*256;
        float acc = 0.f;
        #pragma unroll
        for (int i = 0; i < 16; ++i) acc += yv_l[i*3+m]*W[i*16 + o];
        fvv[n*48 + j] = acc;
    }
}

// ---------------- fused edge kernel: geometry -> MFMA MLP chain -> TP -> ebuf ----------------
__global__ __launch_bounds__(256) void edge_fused_kernel(
    const float* __restrict__ xp,
    const int* __restrict__ srcs, const int* __restrict__ dsts,
    const unsigned short* __restrict__ w1b,   // [64 n][32 k] bf16 (k 16..31 zero)
    const float* __restrict__ b1,
    const unsigned short* __restrict__ w2b,   // [64 n][64 k] bf16
    const float* __restrict__ b2,
    const unsigned short* __restrict__ w3b,   // [192 n][64 k] bf16
    const float* __restrict__ b3,
    const float* __restrict__ fs, const float* __restrict__ fvv,
    unsigned short* __restrict__ ebuf)
{
    __shared__ float wtile[64*193];
    __shared__ unsigned short hbuf[64*72];
    __shared__ float abuf[64*6];
    int lane = threadIdx.x & 63;
    int wid  = threadIdx.x >> 6;
    int eblk = blockIdx.x * 64;
    int row16 = lane & 15, quad = lane >> 4;
    int erow = 16*wid + row16;

    // ---- phase G: lanes 0..15 of each wave: geometry ----
    if (lane < 16) {
        int p = eblk + 16*wid + lane;
        int s = srcs[p], d = dsts[p];
        const float4* xs4 = (const float4*)(xp + (size_t)s*8);
        const float4* xd4 = (const float4*)(xp + (size_t)d*8);
        float4 xsa = xs4[0], xsb = xs4[1];
        float4 xda = xd4[0], xdb = xd4[1];
        float a0[3], a1[3], ef[16];
        {
            float d0 = xsa.x-xda.x, d1 = xsa.y-xda.y, d2 = xsa.z-xda.z;
            float r = sqrtf(d0*d0 + d1*d1 + d2*d2);
            float invr = 1.0f/r;
            float u = 0.8f*r - 2.0f;
            float cut = (u > 0.f) ? 0.f : ((u < -1.f) ? 1.f : 0.5f*(1.f - __cosf(PI_F*u)));
            float sc = 1.7320508075688772f*cut*invr;
            a0[0] = sc*d0; a0[1] = sc*d1; a0[2] = sc*d2;
            float fsc = 2.5298221281347035f*invr;
            #pragma unroll
            for (int k = 0; k < 8; ++k) ef[k] = fsc*__sinf((k+1)*1.2566370614359172f*r);
        }
        {
            float d0 = xsa.w-xda.w, d1 = xsb.x-xdb.x, d2 = xsb.y-xdb.y;
            float r = sqrtf(d0*d0 + d1*d1 + d2*d2);
            float invr = 1.0f/r;
            float u = 0.8f*r - 2.0f;
            float cut = (u > 0.f) ? 0.f : ((u < -1.f) ? 1.f : 0.5f*(1.f - __cosf(PI_F*u)));
            float sc = 1.7320508075688772f*cut*invr;
            a1[0] = sc*d0; a1[1] = sc*d1; a1[2] = sc*d2;
            float fsc = 2.5298221281347035f*invr;
            #pragma unroll
            for (int k = 0; k < 8; ++k) ef[8+k] = fsc*__sinf((k+1)*1.2566370614359172f*r);
        }
        float* ab = abuf + (16*wid + lane)*6;
        ab[0] = a0[0]; ab[1] = a0[1]; ab[2] = a0[2];
        ab[3] = a1[0]; ab[4] = a1[1]; ab[5] = a1[2];
        unsigned epk[8];
        #pragma unroll
        for (int k = 0; k < 8; ++k)
            epk[k] = (unsigned)f2b(ef[2*k]) | ((unsigned)f2b(ef[2*k+1]) << 16);
        uint4* hr = (uint4*)(hbuf + (16*wid + lane)*72);
        uint4 q0; q0.x = epk[0]; q0.y = epk[1]; q0.z = epk[2]; q0.w = epk[3];
        uint4 q1; q1.x = epk[4]; q1.y = epk[5]; q1.z = epk[6]; q1.w = epk[7];
        uint4 qz; qz.x = 0; qz.y = 0; qz.z = 0; qz.w = 0;
        hr[0] = q0; hr[1] = q1; hr[2] = qz; hr[3] = qz;
    }
    // hbuf rows are wave-exclusive; per-wave DS ordering suffices

    // ---- GEMM1: h1 = silu(ef @ W1 + b1), K=32 ----
    {
        short8x a = *(const short8x*)(hbuf + erow*72 + quad*8);
        float4x c[4];
        #pragma unroll
        for (int nt = 0; nt < 4; ++nt) {
            short8x b = *(const short8x*)(w1b + ((size_t)(nt*16 + row16))*32 + quad*8);
            c[nt] = __builtin_amdgcn_mfma_f32_16x16x32_bf16(a, b, (float4x){0.f,0.f,0.f,0.f}, 0, 0, 0);
        }
        #pragma unroll
        for (int nt = 0; nt < 4; ++nt) {
            float bias = b1[nt*16 + row16];
            #pragma unroll
            for (int r = 0; r < 4; ++r) {
                float h = silu(c[nt][r] + bias);
                hbuf[(16*wid + quad*4 + r)*72 + nt*16 + row16] = f2b(h);
            }
        }
    }
    // ---- GEMM2: h2 = silu(h1 @ W2 + b2), K=64 ----
    {
        short8x a0v = *(const short8x*)(hbuf + erow*72 + 0*32 + quad*8);
        short8x a1v = *(const short8x*)(hbuf + erow*72 + 1*32 + quad*8);
        float4x c[4];
        #pragma unroll
        for (int nt = 0; nt < 4; ++nt) {
            short8x b0 = *(const short8x*)(w2b + ((size_t)(nt*16 + row16))*64 + 0*32 + quad*8);
            float4x t = __builtin_amdgcn_mfma_f32_16x16x32_bf16(a0v, b0, (float4x){0.f,0.f,0.f,0.f}, 0, 0, 0);
            short8x b1v = *(const short8x*)(w2b + ((size_t)(nt*16 + row16))*64 + 1*32 + quad*8);
            c[nt] = __builtin_amdgcn_mfma_f32_16x16x32_bf16(a1v, b1v, t, 0, 0, 0);
        }
        #pragma unroll
        for (int nt = 0; nt < 4; ++nt) {
            float bias = b2[nt*16 + row16];
            #pragma unroll
            for (int r = 0; r < 4; ++r) {
                float h = silu(c[nt][r] + bias);
                hbuf[(16*wid + quad*4 + r)*72 + nt*16 + row16] = f2b(h);
            }
        }
    }
    // ---- GEMM3: w = h2 @ W3 (raw, bias later) ----
    {
        short8x a0v = *(const short8x*)(hbuf + erow*72 + 0*32 + quad*8);
        short8x a1v = *(const short8x*)(hbuf + erow*72 + 1*32 + quad*8);
        float4x acc[12];
        #pragma unroll
        for (int nt = 0; nt < 12; ++nt) {
            short8x b0 = *(const short8x*)(w3b + ((size_t)(nt*16 + row16))*64 + 0*32 + quad*8);
            float4x t = __builtin_amdgcn_mfma_f32_16x16x32_bf16(a0v, b0, (float4x){0.f,0.f,0.f,0.f}, 0, 0, 0);
            short8x b1v = *(const short8x*)(w3b + ((size_t)(nt*16 + row16))*64 + 1*32 + quad*8);
            acc[nt] = __builtin_amdgcn_mfma_f32_16x16x32_bf16(a1v, b1v, t, 0, 0, 0);
        }
        #pragma unroll
        for (int nt = 0; nt < 12; ++nt) {
            #pragma unroll
            for (int r = 0; r < 4; ++r) {
                wtile[(16*wid + quad*4 + r)*193 + nt*16 + row16] = acc[nt][r];
            }
        }
    }
    __syncthreads();

    // ---- TP phase: thread (edge = lane, part = wid) ----
    int p = eblk + lane;
    const float* wrow = wtile + lane*193;
    float a0[3], a1[3];
    {
        const float* ab = abuf + lane*6;
        a0[0] = ab[0]; a0[1] = ab[1]; a0[2] = ab[2];
        a1[0] = ab[3]; a1[1] = ab[4]; a1[2] = ab[5];
    }
    int s = srcs[p];
    // o1
    {
        int U0 = 16*wid;
        float fsr[16];
        {
            const float4* f4 = (const float4*)(fs + (size_t)s*64 + U0);
            #pragma unroll
            for (int g = 0; g < 4; ++g) {
                float4 t = f4[g];
                fsr[4*g+0] = t.x; fsr[4*g+1] = t.y; fsr[4*g+2] = t.z; fsr[4*g+3] = t.w;
            }
        }
        #pragma unroll
        for (int uu = 0; uu < 16; ++uu) {
            int u = U0 + uu;
            float su = fsr[uu]*0.125f;   // 1/sqrt(2) * 1/sqrt(32)
            float wa = wrow[2*u]   + b3[2*u];
            float wb = wrow[2*u+1] + b3[2*u+1];
            ebuf[(size_t)(u*3+0)*NEP + p] = f2b(su*(wa*a0[0] + wb*a1[0]));
            ebuf[(size_t)(u*3+1)*NEP + p] = f2b(su*(wa*a0[1] + wb*a1[1]));
            ebuf[(size_t)(u*3+2)*NEP + p] = f2b(su*(wa*a0[2] + wb*a1[2]));
        }
    }
    // o2 + o3
    {
        int U0 = 4*wid;
        float fvr[12];
        {
            const float4* f4 = (const float4*)(fvv + (size_t)s*48 + 3*U0);
            #pragma unroll
            for (int g = 0; g < 3; ++g) {
                float4 t = f4[g];
                fvr[4*g+0] = t.x; fvr[4*g+1] = t.y; fvr[4*g+2] = t.z; fvr[4*g+3] = t.w;
            }
        }
        #pragma unroll
        for (int uu = 0; uu < 4; ++uu) {
            int u = U0 + uu;
            float v0 = fvr[uu*3+0], v1 = fvr[uu*3+1], v2 = fvr[uu*3+2];
            float w2a = wrow[128+2*u] + b3[128+2*u];
            float w2b = wrow[129+2*u] + b3[129+2*u];
            float w3a = wrow[160+2*u] + b3[160+2*u];
            float w3b = wrow[161+2*u] + b3[161+2*u];
            float dd0 = v0*a0[0] + v1*a0[1] + v2*a0[2];
            float dd1 = v0*a1[0] + v1*a1[1] + v2*a1[2];
            ebuf[(size_t)(192+u)*NEP + p] = f2b((w2a*dd0 + w2b*dd1)*0.07216878364870323f); // 1/sqrt(192)
            float c0x = v1*a0[2]-v2*a0[1], c0y = v2*a0[0]-v0*a0[2], c0z = v0*a0[1]-v1*a0[0];
            float c1x = v1*a1[2]-v2*a1[1], c1y = v2*a1[0]-v0*a1[2], c1z = v0*a1[1]-v1*a1[0];
            ebuf[(size_t)(208+u*3+0)*NEP + p] = f2b(0.08838834764831845f*(w3a*c0x + w3b*c1x)); // 1/sqrt(128)
            ebuf[(size_t)(208+u*3+1)*NEP + p] = f2b(0.08838834764831845f*(w3a*c0y + w3b*c1y));
            ebuf[(size_t)(208+u*3+2)*NEP + p] = f2b(0.08838834764831845f*(w3a*c0z + w3b*c1z));
        }
    }
}

// ---------------- segment-sum via LDS transpose tiles ----------------
// block = 16 nodes, 256 threads = 4 waves. Tile = 64 edges.
// Load: wave w stages rows [64w,64w+64) x 64 edges coalesced (lane = edge) into
// stile (stride 66 -> conflict-free). Sum: thread c scans its own row from LDS;
// segment-boundary branches are wave-uniform (same boundaries for all c).
__global__ __launch_bounds__(256) void segsum_kernel(
    const unsigned short* __restrict__ ebuf,
    const int* __restrict__ segoff,
    float* __restrict__ mid)
{
    __shared__ int sbnd[17];
    __shared__ unsigned short stile[256*66];
    int c = threadIdx.x;
    int lane = c & 63, wid = c >> 6;
    int n0 = blockIdx.x * 16;
    if (c < 17) sbnd[c] = segoff[n0 + c];
    __syncthreads();
    int P0 = sbnd[0], P1 = sbnd[16];
    int A = P0 & ~63;
    float cur = 0.f;
    int seg = 0;
    int bnext = sbnd[1];
    const unsigned short* row = stile + c*66;
    for (int base = A; base < P1; base += 64) {
        // stage tile: wave wid loads rows [64*wid, 64*wid+64), column base+lane
        {
            const unsigned short* src = ebuf + (size_t)(64*wid)*NEP + base + lane;
            unsigned short* dst = stile + (64*wid)*66 + lane;
            #pragma unroll
            for (int rr = 0; rr < 64; ++rr)
                dst[rr*66] = src[(size_t)rr*NEP];
        }
        __syncthreads();
        int e0 = (base < P0) ? P0 : base;
        int e1 = (base + 64 < P1) ? (base + 64) : P1;
        for (int e = e0; e < e1; ++e) {
            while (e >= bnext) {   // wave-uniform; never runs seg past 15 (e < P1 = sbnd[16])
                mid[(size_t)(n0 + seg)*256 + c] = cur;
                cur = 0.f; ++seg; bnext = sbnd[seg+1];
            }
            cur += b2f(row[e - base]);
        }
        __syncthreads();
    }
    while (seg < 16) {
        mid[(size_t)(n0 + seg)*256 + c] = cur;
        cur = 0.f; ++seg;
    }
}

// ---------------- node update (256 threads) ----------------
__global__ __launch_bounds__(256) void node_update_kernel(
    const float* __restrict__ ys, const float* __restrict__ yv,
    float* __restrict__ ys_old, float* __restrict__ yv_old,
    const float* __restrict__ mid,
    const int* __restrict__ types,
    const float* __restrict__ scsT, const float* __restrict__ scvT,
    const float* __restrict__ lin2sT, const float* __restrict__ lin2vT,
    const float* __restrict__ siWsT, const float* __restrict__ siWvT,
    const float* __restrict__ Kbuf,
    const float* __restrict__ hv, const float* __restrict__ mixv, int layer,
    float* __restrict__ xpad, float* __restrict__ dout)
{
    int n = blockIdx.x;
    int lane = threadIdx.x;
    __shared__ float ys_l[64], yv_l[48], mids[16], midv[240];
    __shared__ float conv_s[80], conv_v[48], sis_l[64], siv_l[48], yvn[48];
    int t = types[n];
    {
        float v = mid[(size_t)n*256 + lane];
        if (lane < 192) midv[lane] = v;
        else if (lane < 208) mids[lane-192] = v;
        else midv[192 + (lane-208)] = v;
    }
    if (lane < 64) ys_l[lane] = ys[n*64 + lane];
    else if (lane < 112) yv_l[lane-64] = yv[n*48 + (lane-64)];
    __syncthreads();
    if (lane < 80) {
        const float* Wsc = scsT + (size_t)t*5120;
        const float* W2s = lin2sT + (size_t)t*1280;
        float a_sc = 0.f, a_2 = 0.f;
        #pragma unroll
        for (int i = 0; i < 64; ++i) a_sc += ys_l[i]*Wsc[i*80 + lane];
        #pragma unroll
        for (int i = 0; i < 16; ++i) a_2 += mids[i]*W2s[i*80 + lane];
        conv_s[lane] = 0.3826834323650898f*a_sc + 0.9238795325112867f*a_2;
    } else if (lane < 144) {
        int o = lane - 80;
        float a_si = 0.f;
        #pragma unroll
        for (int i = 0; i < 64; ++i) a_si += ys_l[i]*siWsT[i*64 + o];
        sis_l[o] = a_si;
    } else if (lane < 192) {
        int j = lane - 144, o = j/3, m = j%3;
        const float* Wsc = scvT + (size_t)t*256;
        const float* W2v = lin2vT + (size_t)t*1280;
        float a_sc = 0.f, a_2 = 0.f, a_si = 0.f;
        #pragma unroll
        for (int i = 0; i < 16; ++i) {
            float y = yv_l[i*3+m];
            a_sc += y*Wsc[i*16+o];
            a_si += y*siWvT[i*16+o];
        }
        #pragma unroll
        for (int i = 0; i < 80; ++i) a_2 += midv[i*3+m]*W2v[i*16+o];
        conv_v[j] = 0.3826834323650898f*a_sc + 0.9238795325112867f*a_2;
        siv_l[j] = a_si;
    }
    __syncthreads();
    float hh = hv[layer]; float h2c = hh*hh; float mx = mixv[layer];
    if (lane < 64) {
        float cs = conv_s[lane];
        float gns = cs/(1.f + __expf(-cs));
        float ns = 2.f*ys_l[lane] - ys_old[n*64+lane] + h2c*(mx*gns + (mx-1.f)*sis_l[lane]);
        ys_old[n*64+lane] = ns;
    } else if (lane >= 64 && lane < 112) {
        int j = lane-64, o = j/3;
        float g = 1.f/(1.f + __expf(-conv_s[64+o]));
        float gnv = g*conv_v[j];
        float nv = 2.f*yv_l[j] - yv_old[n*48+j] + h2c*(mx*gnv + (mx-1.f)*siv_l[j]);
        yv_old[n*48+j] = nv;
        yvn[j] = nv;
    }
    __syncthreads();
    if (lane < 6) {
        int i = lane/3, m = lane%3;
        float acc = 0.f;
        #pragma unroll
        for (int u = 0; u < 16; ++u) acc += Kbuf[2*u+i]*yvn[u*3+m];
        xpad[n*8 + lane] = acc;
        if (dout) dout[n*6 + lane] = acc;
    }
}

// ---------------- host ----------------
extern "C" void kernel_launch(void* const* d_in, const int* in_sizes, int n_in,
                              void* d_out, int out_size, void* d_ws, size_t ws_size,
                              hipStream_t stream)
{
    const float* x_in   = (const float*)d_in[0];
    const int*   types  = (const int*)  d_in[2];
    const int*   esrc   = (const int*)  d_in[3];
    const int*   edst   = (const int*)  d_in[4];
    const float* emb    = (const float*)d_in[5];
    const float* PU     = (const float*)d_in[6];
    const float* hv     = (const float*)d_in[7];
    const float* mixv   = (const float*)d_in[8];
    const float* si_Ws  = (const float*)d_in[9];
    const float* si_Wv  = (const float*)d_in[10];
    const float* sc_Ws  = (const float*)d_in[11];
    const float* sc_Wv  = (const float*)d_in[12];
    const float* lin1_Ws= (const float*)d_in[13];
    const float* lin1_Wv= (const float*)d_in[14];
    const float* lin2_Ws= (const float*)d_in[15];
    const float* lin2_Wv= (const float*)d_in[16];
    const float* fc_W1  = (const float*)d_in[17];
    const float* fc_b1  = (const float*)d_in[18];
    const float* fc_W2  = (const float*)d_in[19];
    const float* fc_b2  = (const float*)d_in[20];
    const float* fc_W3  = (const float*)d_in[21];
    const float* fc_b3  = (const float*)d_in[22];

    float* ws = (float*)d_ws;
    size_t off = 0;
    auto alloc = [&](size_t nf) { float* p = ws + off; off += nf; return p; };
    float* Kbuf   = alloc(64);
    float* x_pad  = alloc(80000);
    float* ys0    = alloc(640000);
    float* ys1    = alloc(640000);
    float* yv0    = alloc(480000);
    float* yv1    = alloc(480000);
    float* fsb    = alloc(640000);
    float* fvvb   = alloc(480000);
    float* midb   = alloc((size_t)NN*256);
    float* lin1sT = alloc((size_t)4*100*4096);
    float* lin1vT = alloc((size_t)4*100*256);
    float* scsT   = alloc((size_t)4*100*5120);
    float* scvT   = alloc((size_t)4*100*256);
    float* lin2sT = alloc((size_t)4*100*1280);
    float* lin2vT = alloc((size_t)4*100*1280);
    float* siWsT  = alloc((size_t)4*4096);
    float* siWvT  = alloc((size_t)4*256);
    float* W3T    = alloc((size_t)4*12288);
    // int region
    int* iws = (int*)(ws + off);
    size_t ioff = 0;
    auto ialloc = [&](size_t ni) { int* p = iws + ioff; ioff += ni; return p; };
    int* deg    = ialloc(NN);
    int* segoff = ialloc(NN + 8);
    int* cursor = ialloc(NN);
    int* srcs   = ialloc(NE);
    int* dsts   = ialloc(NE);
    // bf16 region (16B-aligned)
    unsigned short* w1bp = (unsigned short*)(iws + ioff);   // [L][64][32]
    unsigned short* w2bp = w1bp + (size_t)4*64*32;          // [L][64][64]
    unsigned short* w3bf = w2bp + (size_t)4*64*64;          // [L][192][64]
    unsigned short* ebuf = w3bf + (size_t)4*192*64;         // [256][NEP]

    // K + state init
    k_newton_kernel<<<1, 1, 0, stream>>>(PU, Kbuf);
    init_xpad_kernel<<<(NN*8 + 255)/256, 256, 0, stream>>>(x_in, x_pad);
    hipMemsetAsync(ys0, 0, 640000*sizeof(float), stream);
    hipMemsetAsync(ys1, 0, 640000*sizeof(float), stream);
    init_yv_kernel<<<(NN*48 + 255)/256, 256, 0, stream>>>(x_in, Kbuf, yv0, yv1);

    const float s2048 = 0.022097086912079608f;
    const float s512  = 0.044194173824159216f;
    const float s2560 = 0.019764235376052372f;
    {
        int tot;
        tot = 4*100*64*64; build_eff_kernel<<<(tot+255)/256,256,0,stream>>>(lin1_Ws, emb, lin1sT, 64, 64, s2048, tot);
        tot = 4*100*16*16; build_eff_kernel<<<(tot+255)/256,256,0,stream>>>(lin1_Wv, emb, lin1vT, 16, 16, s512,  tot);
        tot = 4*100*64*80; build_eff_kernel<<<(tot+255)/256,256,0,stream>>>(sc_Ws,   emb, scsT,   80, 64, s2048, tot);
        tot = 4*100*16*16; build_eff_kernel<<<(tot+255)/256,256,0,stream>>>(sc_Wv,   emb, scvT,   16, 16, s512,  tot);
        tot = 4*100*16*80; build_eff_kernel<<<(tot+255)/256,256,0,stream>>>(lin2_Ws, emb, lin2sT, 80, 16, s512,  tot);
        tot = 4*100*80*16; build_eff_kernel<<<(tot+255)/256,256,0,stream>>>(lin2_Wv, emb, lin2vT, 16, 80, s2560, tot);
        tot = 4*64*64;  transpose_kernel<<<(tot+255)/256,256,0,stream>>>(si_Ws, siWsT, 64, 64, 0.125f, tot);
        tot = 4*16*16;  transpose_kernel<<<(tot+255)/256,256,0,stream>>>(si_Wv, siWvT, 16, 16, 0.25f,  tot);
        tot = 4*64*192; transpose_kernel<<<(tot+255)/256,256,0,stream>>>(fc_W3, W3T, 64, 192, 1.0f, tot);
        tot = 4*192*64; cast_bf16_kernel<<<(tot+255)/256,256,0,stream>>>(W3T, w3bf, tot);
        tot = 4*64*32;  pack_w_kernel<<<(tot+255)/256,256,0,stream>>>(fc_W1, w1bp, 16, 64, 32, tot);
        tot = 4*64*64;  pack_w_kernel<<<(tot+255)/256,256,0,stream>>>(fc_W2, w2bp, 64, 64, 64, tot);
    }

    // counting sort by dst
    hipMemsetAsync(deg, 0, NN*sizeof(int), stream);
    hist_kernel<<<(NE+255)/256, 256, 0, stream>>>(edst, deg);
    scan_kernel<<<1, 256, 0, stream>>>(deg, segoff, cursor);
    scatter_kernel<<<(NE+255)/256, 256, 0, stream>>>(esrc, edst, cursor, srcs, dsts);

    float* ys_cur = ys0; float* ys_old = ys1;
    float* yv_cur = yv0; float* yv_old = yv1;
    for (int l = 0; l < 4; ++l) {
        node_lin1_kernel<<<NN, 128, 0, stream>>>(
            ys_cur, yv_cur, types,
            lin1sT + (size_t)l*100*4096, lin1vT + (size_t)l*100*256,
            fsb, fvvb);
        edge_fused_kernel<<<NE/64, 256, 0, stream>>>(
            x_pad, srcs, dsts,
            w1bp + (size_t)l*64*32,  fc_b1 + (size_t)l*64,
            w2bp + (size_t)l*64*64,  fc_b2 + (size_t)l*64,
            w3bf + (size_t)l*192*64, fc_b3 + (size_t)l*192,
            fsb, fvvb, ebuf);
        segsum_kernel<<<NN/16, 256, 0, stream>>>(ebuf, segoff, midb);
        node_update_kernel<<<NN, 256, 0, stream>>>(
            ys_cur, yv_cur, ys_old, yv_old,
            midb, types,
            scsT   + (size_t)l*100*5120, scvT   + (size_t)l*100*256,
            lin2sT + (size_t)l*100*1280, lin2vT + (size_t)l*100*1280,
            siWsT  + (size_t)l*4096,     siWvT  + (size_t)l*256,
            Kbuf, hv, mixv, l, x_pad, (l == 3) ? (float*)d_out : nullptr);
        float* tmp;
        tmp = ys_cur; ys_cur = ys_old; ys_old = tmp;
        tmp = yv_cur; yv_cur = yv_old; yv_old = tmp;
    }
}

// Round 8
// 1229.162 us; speedup vs baseline: 2.0548x; 1.0540x over previous
//
#include <hip/hip_runtime.h>
#include <math.h>

#define NN 10000
#define NE 320000
#define NEP (NE + 64)      // padded ebuf row stride
#define PI_F 3.14159265358979323846f

typedef __attribute__((ext_vector_type(8))) short short8x;
typedef __attribute__((ext_vector_type(8))) unsigned short ushort8x;
typedef __attribute__((ext_vector_type(4))) float float4x;

__device__ __forceinline__ unsigned short f2b(float f) {
    unsigned b = __float_as_uint(f);
    return (unsigned short)((b + 0x7FFFu + ((b >> 16) & 1u)) >> 16);
}
__device__ __forceinline__ float b2f(unsigned short u) {
    return __uint_as_float(((unsigned)u) << 16);
}
__device__ __forceinline__ float silu(float x) {
    return x / (1.f + __expf(-x));
}

// ---------------- K = Newton-Schulz semi-unitary (16x2) ----------------
__global__ void k_newton_kernel(const float* __restrict__ PU, float* __restrict__ Kout)
{
    if (threadIdx.x != 0 || blockIdx.x != 0) return;
    float K[32];
    float nrm = 0.f;
    for (int i = 0; i < 32; ++i) { K[i] = PU[i]; nrm += K[i]*K[i]; }
    float inv = 1.0f / sqrtf(nrm);
    for (int i = 0; i < 32; ++i) K[i] *= inv;
    for (int it = 0; it < 10; ++it) {
        float m00 = 0.f, m01 = 0.f, m11 = 0.f;
        for (int u = 0; u < 16; ++u) {
            float a = K[2*u], b = K[2*u+1];
            m00 += a*a; m01 += a*b; m11 += b*b;
        }
        for (int u = 0; u < 16; ++u) {
            float a = K[2*u], b = K[2*u+1];
            K[2*u]   = 1.5f*a - 0.5f*(a*m00 + b*m01);
            K[2*u+1] = 1.5f*b - 0.5f*(a*m01 + b*m11);
        }
    }
    for (int i = 0; i < 32; ++i) Kout[i] = K[i];
}

// ---------------- x_pad init: (N,6) -> (N,8) ----------------
__global__ void init_xpad_kernel(const float* __restrict__ x, float* __restrict__ xp)
{
    int tid = blockIdx.x*blockDim.x + threadIdx.x;
    if (tid >= NN*8) return;
    int n = tid >> 3, c = tid & 7;
    xp[tid] = (c < 6) ? x[n*6 + c] : 0.f;
}

// ---------------- yv init ----------------
__global__ void init_yv_kernel(const float* __restrict__ x, const float* __restrict__ K,
                               float* __restrict__ yv0, float* __restrict__ yv1)
{
    int tid = blockIdx.x*blockDim.x + threadIdx.x;
    if (tid >= NN*48) return;
    int n = tid/48, j = tid%48, u = j/3, m = j%3;
    float v = K[2*u]*x[n*6+m] + K[2*u+1]*x[n*6+3+m];
    yv0[tid] = v; yv1[tid] = v;
}

// ---------------- layer-0 fvv init (fs0 = 0 since ys0 = 0) ----------------
__global__ void init_fvv_kernel(const float* __restrict__ yv, const int* __restrict__ types,
                                const float* __restrict__ lin1vT0, float* __restrict__ fvv)
{
    int tid = blockIdx.x*blockDim.x + threadIdx.x;
    if (tid >= NN*48) return;
    int n = tid/48, j = tid%48, o = j/3, m = j%3;
    int t = types[n];
    const float* W = lin1vT0 + (size_t)t*256;
    float acc = 0.f;
    #pragma unroll
    for (int i = 0; i < 16; ++i) acc += yv[n*48 + i*3 + m]*W[i*16 + o];
    fvv[tid] = acc;
}

// ---------------- per-type effective weights ----------------
__global__ void build_eff_kernel(const float* __restrict__ W, const float* __restrict__ emb,
                                 float* __restrict__ out, int O, int I, float scale, int total)
{
    int tid = blockIdx.x*blockDim.x + threadIdx.x;
    if (tid >= total) return;
    int o = tid % O; int r = tid / O;
    int i = r % I; r /= I;
    int t = r % 100; int l = r / 100;
    const float* w  = W + (((size_t)l*O + o)*I + i)*32;
    const float* em = emb + (size_t)t*32;
    float acc = 0.f;
    #pragma unroll
    for (int e = 0; e < 32; ++e) acc += w[e]*em[e];
    out[tid] = acc*scale;
}

// ---------------- transpose (L,O,I) -> (L,I,O), scaled ----------------
__global__ void transpose_kernel(const float* __restrict__ W, float* __restrict__ out,
                                 int O, int I, float scale, int total)
{
    int tid = blockIdx.x*blockDim.x + threadIdx.x;
    if (tid >= total) return;
    int o = tid % O; int r = tid / O;
    int i = r % I; int l = r / I;
    out[tid] = W[((size_t)l*O + o)*I + i]*scale;
}

// ---------------- f32 -> bf16 cast ----------------
__global__ void cast_bf16_kernel(const float* __restrict__ in, unsigned short* __restrict__ out, int total)
{
    int tid = blockIdx.x*blockDim.x + threadIdx.x;
    if (tid < total) out[tid] = f2b(in[tid]);
}

// ---------------- pack MLP weight [L][K][N] -> bf16 [L][N][KP] (zero-pad K->KP) ----------------
__global__ void pack_w_kernel(const float* __restrict__ W, unsigned short* __restrict__ out,
                              int K, int N, int KP, int total)
{
    int tid = blockIdx.x*blockDim.x + threadIdx.x;
    if (tid >= total) return;
    int kk = tid % KP; int r = tid / KP;
    int n = r % N; int l = r / N;
    float v = (kk < K) ? W[((size_t)l*K + kk)*N + n] : 0.f;
    out[tid] = f2b(v);
}

// ---------------- counting sort by dst ----------------
__global__ void hist_kernel(const int* __restrict__ dst, int* __restrict__ deg)
{
    int e = blockIdx.x*256 + threadIdx.x;
    if (e < NE) atomicAdd(&deg[dst[e]], 1);
}

__global__ __launch_bounds__(256) void scan_kernel(const int* __restrict__ deg,
                                                   int* __restrict__ segoff,
                                                   int* __restrict__ cursor)
{
    __shared__ int part[256];
    int tid = threadIdx.x;
    int base = tid*40;
    int s = 0;
    for (int i = 0; i < 40; ++i) { int idx = base+i; if (idx < NN) s += deg[idx]; }
    part[tid] = s;
    __syncthreads();
    for (int o = 1; o < 256; o <<= 1) {
        int v = (tid >= o) ? part[tid-o] : 0;
        __syncthreads();
        part[tid] += v;
        __syncthreads();
    }
    int excl = part[tid] - s;
    for (int i = 0; i < 40; ++i) {
        int idx = base+i;
        if (idx < NN) { segoff[idx] = excl; cursor[idx] = excl; excl += deg[idx]; }
        else if (idx == NN) { segoff[NN] = excl; }
    }
}

__global__ void scatter_kernel(const int* __restrict__ src, const int* __restrict__ dst,
                               int* __restrict__ cursor,
                               int* __restrict__ srcs, int* __restrict__ dsts)
{
    int e = blockIdx.x*256 + threadIdx.x;
    if (e >= NE) return;
    int d = dst[e];
    int p = atomicAdd(&cursor[d], 1);
    srcs[p] = src[e]; dsts[p] = d;
}

// ---------------- fused edge kernel: geometry -> MFMA MLP chain -> TP -> ebuf ----------------
// LDS: wbuf bf16 [64][194] (24.8 KB) + hbuf [64][72] bf16 (9.2 KB) + abuf (1.5 KB)
// => ~35.6 KB -> 4 blocks/CU (was 60.4 KB -> 2).
__global__ __launch_bounds__(256) void edge_fused_kernel(
    const float* __restrict__ xp,
    const int* __restrict__ srcs, const int* __restrict__ dsts,
    const unsigned short* __restrict__ w1b,   // [64 n][32 k] bf16 (k 16..31 zero)
    const float* __restrict__ b1,
    const unsigned short* __restrict__ w2b,   // [64 n][64 k] bf16
    const float* __restrict__ b2,
    const unsigned short* __restrict__ w3b,   // [192 n][64 k] bf16
    const float* __restrict__ b3,
    const float* __restrict__ fs, const float* __restrict__ fvv,
    unsigned short* __restrict__ ebuf)
{
    __shared__ unsigned short wbuf[64*194];
    __shared__ unsigned short hbuf[64*72];
    __shared__ float abuf[64*6];
    int lane = threadIdx.x & 63;
    int wid  = threadIdx.x >> 6;
    int eblk = blockIdx.x * 64;
    int row16 = lane & 15, quad = lane >> 4;
    int erow = 16*wid + row16;

    // ---- phase G: lanes 0..15 of each wave: geometry ----
    if (lane < 16) {
        int p = eblk + 16*wid + lane;
        int s = srcs[p], d = dsts[p];
        const float4* xs4 = (const float4*)(xp + (size_t)s*8);
        const float4* xd4 = (const float4*)(xp + (size_t)d*8);
        float4 xsa = xs4[0], xsb = xs4[1];
        float4 xda = xd4[0], xdb = xd4[1];
        float a0[3], a1[3], ef[16];
        {
            float d0 = xsa.x-xda.x, d1 = xsa.y-xda.y, d2 = xsa.z-xda.z;
            float r = sqrtf(d0*d0 + d1*d1 + d2*d2);
            float invr = 1.0f/r;
            float u = 0.8f*r - 2.0f;
            float cut = (u > 0.f) ? 0.f : ((u < -1.f) ? 1.f : 0.5f*(1.f - __cosf(PI_F*u)));
            float sc = 1.7320508075688772f*cut*invr;
            a0[0] = sc*d0; a0[1] = sc*d1; a0[2] = sc*d2;
            float fsc = 2.5298221281347035f*invr;
            #pragma unroll
            for (int k = 0; k < 8; ++k) ef[k] = fsc*__sinf((k+1)*1.2566370614359172f*r);
        }
        {
            float d0 = xsa.w-xda.w, d1 = xsb.x-xdb.x, d2 = xsb.y-xdb.y;
            float r = sqrtf(d0*d0 + d1*d1 + d2*d2);
            float invr = 1.0f/r;
            float u = 0.8f*r - 2.0f;
            float cut = (u > 0.f) ? 0.f : ((u < -1.f) ? 1.f : 0.5f*(1.f - __cosf(PI_F*u)));
            float sc = 1.7320508075688772f*cut*invr;
            a1[0] = sc*d0; a1[1] = sc*d1; a1[2] = sc*d2;
            float fsc = 2.5298221281347035f*invr;
            #pragma unroll
            for (int k = 0; k < 8; ++k) ef[8+k] = fsc*__sinf((k+1)*1.2566370614359172f*r);
        }
        float* ab = abuf + (16*wid + lane)*6;
        ab[0] = a0[0]; ab[1] = a0[1]; ab[2] = a0[2];
        ab[3] = a1[0]; ab[4] = a1[1]; ab[5] = a1[2];
        unsigned epk[8];
        #pragma unroll
        for (int k = 0; k < 8; ++k)
            epk[k] = (unsigned)f2b(ef[2*k]) | ((unsigned)f2b(ef[2*k+1]) << 16);
        uint4* hr = (uint4*)(hbuf + (16*wid + lane)*72);
        uint4 q0; q0.x = epk[0]; q0.y = epk[1]; q0.z = epk[2]; q0.w = epk[3];
        uint4 q1; q1.x = epk[4]; q1.y = epk[5]; q1.z = epk[6]; q1.w = epk[7];
        uint4 qz; qz.x = 0; qz.y = 0; qz.z = 0; qz.w = 0;
        hr[0] = q0; hr[1] = q1; hr[2] = qz; hr[3] = qz;
    }
    // hbuf rows are wave-exclusive; per-wave DS ordering suffices

    // ---- GEMM1: h1 = silu(ef @ W1 + b1), K=32 ----
    {
        short8x a = *(const short8x*)(hbuf + erow*72 + quad*8);
        float4x c[4];
        #pragma unroll
        for (int nt = 0; nt < 4; ++nt) {
            short8x b = *(const short8x*)(w1b + ((size_t)(nt*16 + row16))*32 + quad*8);
            c[nt] = __builtin_amdgcn_mfma_f32_16x16x32_bf16(a, b, (float4x){0.f,0.f,0.f,0.f}, 0, 0, 0);
        }
        #pragma unroll
        for (int nt = 0; nt < 4; ++nt) {
            float bias = b1[nt*16 + row16];
            #pragma unroll
            for (int r = 0; r < 4; ++r) {
                float h = silu(c[nt][r] + bias);
                hbuf[(16*wid + quad*4 + r)*72 + nt*16 + row16] = f2b(h);
            }
        }
    }
    // ---- GEMM2: h2 = silu(h1 @ W2 + b2), K=64 ----
    {
        short8x a0v = *(const short8x*)(hbuf + erow*72 + 0*32 + quad*8);
        short8x a1v = *(const short8x*)(hbuf + erow*72 + 1*32 + quad*8);
        float4x c[4];
        #pragma unroll
        for (int nt = 0; nt < 4; ++nt) {
            short8x b0 = *(const short8x*)(w2b + ((size_t)(nt*16 + row16))*64 + 0*32 + quad*8);
            float4x t = __builtin_amdgcn_mfma_f32_16x16x32_bf16(a0v, b0, (float4x){0.f,0.f,0.f,0.f}, 0, 0, 0);
            short8x b1v = *(const short8x*)(w2b + ((size_t)(nt*16 + row16))*64 + 1*32 + quad*8);
            c[nt] = __builtin_amdgcn_mfma_f32_16x16x32_bf16(a1v, b1v, t, 0, 0, 0);
        }
        #pragma unroll
        for (int nt = 0; nt < 4; ++nt) {
            float bias = b2[nt*16 + row16];
            #pragma unroll
            for (int r = 0; r < 4; ++r) {
                float h = silu(c[nt][r] + bias);
                hbuf[(16*wid + quad*4 + r)*72 + nt*16 + row16] = f2b(h);
            }
        }
    }
    // ---- GEMM3: w = h2 @ W3 (raw bf16 into wbuf, bias added in TP) ----
    {
        short8x a0v = *(const short8x*)(hbuf + erow*72 + 0*32 + quad*8);
        short8x a1v = *(const short8x*)(hbuf + erow*72 + 1*32 + quad*8);
        float4x acc[12];
        #pragma unroll
        for (int nt = 0; nt < 12; ++nt) {
            short8x b0 = *(const short8x*)(w3b + ((size_t)(nt*16 + row16))*64 + 0*32 + quad*8);
            float4x t = __builtin_amdgcn_mfma_f32_16x16x32_bf16(a0v, b0, (float4x){0.f,0.f,0.f,0.f}, 0, 0, 0);
            short8x b1v = *(const short8x*)(w3b + ((size_t)(nt*16 + row16))*64 + 1*32 + quad*8);
            acc[nt] = __builtin_amdgcn_mfma_f32_16x16x32_bf16(a1v, b1v, t, 0, 0, 0);
        }
        #pragma unroll
        for (int nt = 0; nt < 12; ++nt) {
            #pragma unroll
            for (int r = 0; r < 4; ++r) {
                wbuf[(16*wid + quad*4 + r)*194 + nt*16 + row16] = f2b(acc[nt][r]);
            }
        }
    }
    __syncthreads();

    // ---- TP phase: thread (edge = lane, part = wid) ----
    int p = eblk + lane;
    const unsigned short* wrow = wbuf + lane*194;
    float a0[3], a1[3];
    {
        const float* ab = abuf + lane*6;
        a0[0] = ab[0]; a0[1] = ab[1]; a0[2] = ab[2];
        a1[0] = ab[3]; a1[1] = ab[4]; a1[2] = ab[5];
    }
    int s = srcs[p];
    // o1
    {
        int U0 = 16*wid;
        float fsr[16];
        {
            const float4* f4 = (const float4*)(fs + (size_t)s*64 + U0);
            #pragma unroll
            for (int g = 0; g < 4; ++g) {
                float4 t = f4[g];
                fsr[4*g+0] = t.x; fsr[4*g+1] = t.y; fsr[4*g+2] = t.z; fsr[4*g+3] = t.w;
            }
        }
        #pragma unroll
        for (int uu = 0; uu < 16; ++uu) {
            int u = U0 + uu;
            float su = fsr[uu]*0.125f;   // 1/sqrt(2) * 1/sqrt(32)
            unsigned pr = *(const unsigned*)(wrow + 2*u);
            float wa = b2f((unsigned short)(pr & 0xffffu)) + b3[2*u];
            float wb = b2f((unsigned short)(pr >> 16))     + b3[2*u+1];
            ebuf[(size_t)(u*3+0)*NEP + p] = f2b(su*(wa*a0[0] + wb*a1[0]));
            ebuf[(size_t)(u*3+1)*NEP + p] = f2b(su*(wa*a0[1] + wb*a1[1]));
            ebuf[(size_t)(u*3+2)*NEP + p] = f2b(su*(wa*a0[2] + wb*a1[2]));
        }
    }
    // o2 + o3
    {
        int U0 = 4*wid;
        float fvr[12];
        {
            const float4* f4 = (const float4*)(fvv + (size_t)s*48 + 3*U0);
            #pragma unroll
            for (int g = 0; g < 3; ++g) {
                float4 t = f4[g];
                fvr[4*g+0] = t.x; fvr[4*g+1] = t.y; fvr[4*g+2] = t.z; fvr[4*g+3] = t.w;
            }
        }
        #pragma unroll
        for (int uu = 0; uu < 4; ++uu) {
            int u = U0 + uu;
            float v0 = fvr[uu*3+0], v1 = fvr[uu*3+1], v2 = fvr[uu*3+2];
            unsigned p2 = *(const unsigned*)(wrow + 128 + 2*u);
            unsigned p3 = *(const unsigned*)(wrow + 160 + 2*u);
            float w2a = b2f((unsigned short)(p2 & 0xffffu)) + b3[128+2*u];
            float w2b = b2f((unsigned short)(p2 >> 16))     + b3[129+2*u];
            float w3a = b2f((unsigned short)(p3 & 0xffffu)) + b3[160+2*u];
            float w3b = b2f((unsigned short)(p3 >> 16))     + b3[161+2*u];
            float dd0 = v0*a0[0] + v1*a0[1] + v2*a0[2];
            float dd1 = v0*a1[0] + v1*a1[1] + v2*a1[2];
            ebuf[(size_t)(192+u)*NEP + p] = f2b((w2a*dd0 + w2b*dd1)*0.07216878364870323f); // 1/sqrt(192)
            float c0x = v1*a0[2]-v2*a0[1], c0y = v2*a0[0]-v0*a0[2], c0z = v0*a0[1]-v1*a0[0];
            float c1x = v1*a1[2]-v2*a1[1], c1y = v2*a1[0]-v0*a1[2], c1z = v0*a1[1]-v1*a1[0];
            ebuf[(size_t)(208+u*3+0)*NEP + p] = f2b(0.08838834764831845f*(w3a*c0x + w3b*c1x)); // 1/sqrt(128)
            ebuf[(size_t)(208+u*3+1)*NEP + p] = f2b(0.08838834764831845f*(w3a*c0y + w3b*c1y));
            ebuf[(size_t)(208+u*3+2)*NEP + p] = f2b(0.08838834764831845f*(w3a*c0z + w3b*c1z));
        }
    }
}

// ---------------- segment-sum via LDS transpose tiles ----------------
__global__ __launch_bounds__(256) void segsum_kernel(
    const unsigned short* __restrict__ ebuf,
    const int* __restrict__ segoff,
    float* __restrict__ mid)
{
    __shared__ int sbnd[17];
    __shared__ unsigned short stile[256*66];
    int c = threadIdx.x;
    int lane = c & 63, wid = c >> 6;
    int n0 = blockIdx.x * 16;
    if (c < 17) sbnd[c] = segoff[n0 + c];
    __syncthreads();
    int P0 = sbnd[0], P1 = sbnd[16];
    int A = P0 & ~63;
    float cur = 0.f;
    int seg = 0;
    int bnext = sbnd[1];
    const unsigned short* row = stile + c*66;
    for (int base = A; base < P1; base += 64) {
        {
            const unsigned short* src = ebuf + (size_t)(64*wid)*NEP + base + lane;
            unsigned short* dst = stile + (64*wid)*66 + lane;
            #pragma unroll
            for (int rr = 0; rr < 64; ++rr)
                dst[rr*66] = src[(size_t)rr*NEP];
        }
        __syncthreads();
        int e0 = (base < P0) ? P0 : base;
        int e1 = (base + 64 < P1) ? (base + 64) : P1;
        for (int e = e0; e < e1; ++e) {
            while (e >= bnext) {
                mid[(size_t)(n0 + seg)*256 + c] = cur;
                cur = 0.f; ++seg; bnext = sbnd[seg+1];
            }
            cur += b2f(row[e - base]);
        }
        __syncthreads();
    }
    while (seg < 16) {
        mid[(size_t)(n0 + seg)*256 + c] = cur;
        cur = 0.f; ++seg;
    }
}

// ---------------- node update + fused next-layer lin1 ----------------
__global__ __launch_bounds__(256) void node_update_kernel(
    const float* __restrict__ ys, const float* __restrict__ yv,
    float* __restrict__ ys_old, float* __restrict__ yv_old,
    const float* __restrict__ mid,
    const int* __restrict__ types,
    const float* __restrict__ scsT, const float* __restrict__ scvT,
    const float* __restrict__ lin2sT, const float* __restrict__ lin2vT,
    const float* __restrict__ siWsT, const float* __restrict__ siWvT,
    const float* __restrict__ lin1sTn, const float* __restrict__ lin1vTn, // next layer
    const float* __restrict__ Kbuf,
    const float* __restrict__ hv, const float* __restrict__ mixv, int layer,
    float* __restrict__ fs_out, float* __restrict__ fvv_out,
    float* __restrict__ xpad, float* __restrict__ dout)
{
    int n = blockIdx.x;
    int lane = threadIdx.x;
    __shared__ float ys_l[64], yv_l[48], mids[16], midv[240];
    __shared__ float conv_s[80], conv_v[48], sis_l[64], siv_l[48], ysn[64], yvn[48];
    int t = types[n];
    {
        float v = mid[(size_t)n*256 + lane];
        if (lane < 192) midv[lane] = v;
        else if (lane < 208) mids[lane-192] = v;
        else midv[192 + (lane-208)] = v;
    }
    if (lane < 64) ys_l[lane] = ys[n*64 + lane];
    else if (lane < 112) yv_l[lane-64] = yv[n*48 + (lane-64)];
    __syncthreads();
    if (lane < 80) {
        const float* Wsc = scsT + (size_t)t*5120;
        const float* W2s = lin2sT + (size_t)t*1280;
        float a_sc = 0.f, a_2 = 0.f;
        #pragma unroll
        for (int i = 0; i < 64; ++i) a_sc += ys_l[i]*Wsc[i*80 + lane];
        #pragma unroll
        for (int i = 0; i < 16; ++i) a_2 += mids[i]*W2s[i*80 + lane];
        conv_s[lane] = 0.3826834323650898f*a_sc + 0.9238795325112867f*a_2;
    } else if (lane < 144) {
        int o = lane - 80;
        float a_si = 0.f;
        #pragma unroll
        for (int i = 0; i < 64; ++i) a_si += ys_l[i]*siWsT[i*64 + o];
        sis_l[o] = a_si;
    } else if (lane < 192) {
        int j = lane - 144, o = j/3, m = j%3;
        const float* Wsc = scvT + (size_t)t*256;
        const float* W2v = lin2vT + (size_t)t*1280;
        float a_sc = 0.f, a_2 = 0.f, a_si = 0.f;
        #pragma unroll
        for (int i = 0; i < 16; ++i) {
            float y = yv_l[i*3+m];
            a_sc += y*Wsc[i*16+o];
            a_si += y*siWvT[i*16+o];
        }
        #pragma unroll
        for (int i = 0; i < 80; ++i) a_2 += midv[i*3+m]*W2v[i*16+o];
        conv_v[j] = 0.3826834323650898f*a_sc + 0.9238795325112867f*a_2;
        siv_l[j] = a_si;
    }
    __syncthreads();
    float hh = hv[layer]; float h2c = hh*hh; float mx = mixv[layer];
    if (lane < 64) {
        float cs = conv_s[lane];
        float gns = cs/(1.f + __expf(-cs));
        float ns = 2.f*ys_l[lane] - ys_old[n*64+lane] + h2c*(mx*gns + (mx-1.f)*sis_l[lane]);
        ys_old[n*64+lane] = ns;
        ysn[lane] = ns;
    } else if (lane < 112) {
        int j = lane-64, o = j/3;
        float g = 1.f/(1.f + __expf(-conv_s[64+o]));
        float gnv = g*conv_v[j];
        float nv = 2.f*yv_l[j] - yv_old[n*48+j] + h2c*(mx*gnv + (mx-1.f)*siv_l[j]);
        yv_old[n*48+j] = nv;
        yvn[j] = nv;
    }
    __syncthreads();
    if (lane < 6) {
        int i = lane/3, m = lane%3;
        float acc = 0.f;
        #pragma unroll
        for (int u = 0; u < 16; ++u) acc += Kbuf[2*u+i]*yvn[u*3+m];
        xpad[n*8 + lane] = acc;
        if (dout) dout[n*6 + lane] = acc;
    }
    // fused next-layer lin1
    if (lane < 64) {
        const float* W = lin1sTn + (size_t)t*4096;
        float acc = 0.f;
        #pragma unroll
        for (int i = 0; i < 64; ++i) acc += ysn[i]*W[i*64 + lane];
        fs_out[n*64 + lane] = acc;
    } else if (lane < 112) {
        int j = lane - 64, o = j/3, m = j%3;
        const float* W = lin1vTn + (size_t)t*256;
        float acc = 0.f;
        #pragma unroll
        for (int i = 0; i < 16; ++i) acc += yvn[i*3+m]*W[i*16 + o];
        fvv_out[n*48 + j] = acc;
    }
}

// ---------------- host ----------------
extern "C" void kernel_launch(void* const* d_in, const int* in_sizes, int n_in,
                              void* d_out, int out_size, void* d_ws, size_t ws_size,
                              hipStream_t stream)
{
    const float* x_in   = (const float*)d_in[0];
    const int*   types  = (const int*)  d_in[2];
    const int*   esrc   = (const int*)  d_in[3];
    const int*   edst   = (const int*)  d_in[4];
    const float* emb    = (const float*)d_in[5];
    const float* PU     = (const float*)d_in[6];
    const float* hv     = (const float*)d_in[7];
    const float* mixv   = (const float*)d_in[8];
    const float* si_Ws  = (const float*)d_in[9];
    const float* si_Wv  = (const float*)d_in[10];
    const float* sc_Ws  = (const float*)d_in[11];
    const float* sc_Wv  = (const float*)d_in[12];
    const float* lin1_Ws= (const float*)d_in[13];
    const float* lin1_Wv= (const float*)d_in[14];
    const float* lin2_Ws= (const float*)d_in[15];
    const float* lin2_Wv= (const float*)d_in[16];
    const float* fc_W1  = (const float*)d_in[17];
    const float* fc_b1  = (const float*)d_in[18];
    const float* fc_W2  = (const float*)d_in[19];
    const float* fc_b2  = (const float*)d_in[20];
    const float* fc_W3  = (const float*)d_in[21];
    const float* fc_b3  = (const float*)d_in[22];

    float* ws = (float*)d_ws;
    size_t off = 0;
    auto alloc = [&](size_t nf) { float* p = ws + off; off += nf; return p; };
    float* Kbuf   = alloc(64);
    float* x_pad  = alloc(80000);
    float* ys0    = alloc(640000);
    float* ys1    = alloc(640000);
    float* yv0    = alloc(480000);
    float* yv1    = alloc(480000);
    float* fsb    = alloc(640000);
    float* fvvb   = alloc(480000);
    float* midb   = alloc((size_t)NN*256);
    float* lin1sT = alloc((size_t)4*100*4096);
    float* lin1vT = alloc((size_t)4*100*256);
    float* scsT   = alloc((size_t)4*100*5120);
    float* scvT   = alloc((size_t)4*100*256);
    float* lin2sT = alloc((size_t)4*100*1280);
    float* lin2vT = alloc((size_t)4*100*1280);
    float* siWsT  = alloc((size_t)4*4096);
    float* siWvT  = alloc((size_t)4*256);
    float* W3T    = alloc((size_t)4*12288);
    // int region
    int* iws = (int*)(ws + off);
    size_t ioff = 0;
    auto ialloc = [&](size_t ni) { int* p = iws + ioff; ioff += ni; return p; };
    int* deg    = ialloc(NN);
    int* segoff = ialloc(NN + 8);
    int* cursor = ialloc(NN);
    int* srcs   = ialloc(NE);
    int* dsts   = ialloc(NE);
    // bf16 region (16B-aligned)
    unsigned short* w1bp = (unsigned short*)(iws + ioff);   // [L][64][32]
    unsigned short* w2bp = w1bp + (size_t)4*64*32;          // [L][64][64]
    unsigned short* w3bf = w2bp + (size_t)4*64*64;          // [L][192][64]
    unsigned short* ebuf = w3bf + (size_t)4*192*64;         // [256][NEP]

    // K + state init
    k_newton_kernel<<<1, 1, 0, stream>>>(PU, Kbuf);
    init_xpad_kernel<<<(NN*8 + 255)/256, 256, 0, stream>>>(x_in, x_pad);
    hipMemsetAsync(ys0, 0, 640000*sizeof(float), stream);
    hipMemsetAsync(ys1, 0, 640000*sizeof(float), stream);
    hipMemsetAsync(fsb, 0, 640000*sizeof(float), stream);   // fs layer 0 = 0 (ys0 = 0)
    init_yv_kernel<<<(NN*48 + 255)/256, 256, 0, stream>>>(x_in, Kbuf, yv0, yv1);

    const float s2048 = 0.022097086912079608f;
    const float s512  = 0.044194173824159216f;
    const float s2560 = 0.019764235376052372f;
    {
        int tot;
        tot = 4*100*64*64; build_eff_kernel<<<(tot+255)/256,256,0,stream>>>(lin1_Ws, emb, lin1sT, 64, 64, s2048, tot);
        tot = 4*100*16*16; build_eff_kernel<<<(tot+255)/256,256,0,stream>>>(lin1_Wv, emb, lin1vT, 16, 16, s512,  tot);
        tot = 4*100*64*80; build_eff_kernel<<<(tot+255)/256,256,0,stream>>>(sc_Ws,   emb, scsT,   80, 64, s2048, tot);
        tot = 4*100*16*16; build_eff_kernel<<<(tot+255)/256,256,0,stream>>>(sc_Wv,   emb, scvT,   16, 16, s512,  tot);
        tot = 4*100*16*80; build_eff_kernel<<<(tot+255)/256,256,0,stream>>>(lin2_Ws, emb, lin2sT, 80, 16, s512,  tot);
        tot = 4*100*80*16; build_eff_kernel<<<(tot+255)/256,256,0,stream>>>(lin2_Wv, emb, lin2vT, 16, 80, s2560, tot);
        tot = 4*64*64;  transpose_kernel<<<(tot+255)/256,256,0,stream>>>(si_Ws, siWsT, 64, 64, 0.125f, tot);
        tot = 4*16*16;  transpose_kernel<<<(tot+255)/256,256,0,stream>>>(si_Wv, siWvT, 16, 16, 0.25f,  tot);
        tot = 4*64*192; transpose_kernel<<<(tot+255)/256,256,0,stream>>>(fc_W3, W3T, 64, 192, 1.0f, tot);
        tot = 4*192*64; cast_bf16_kernel<<<(tot+255)/256,256,0,stream>>>(W3T, w3bf, tot);
        tot = 4*64*32;  pack_w_kernel<<<(tot+255)/256,256,0,stream>>>(fc_W1, w1bp, 16, 64, 32, tot);
        tot = 4*64*64;  pack_w_kernel<<<(tot+255)/256,256,0,stream>>>(fc_W2, w2bp, 64, 64, 64, tot);
    }
    // layer-0 fvv (after lin1vT built)
    init_fvv_kernel<<<(NN*48 + 255)/256, 256, 0, stream>>>(yv0, types, lin1vT, fvvb);

    // counting sort by dst
    hipMemsetAsync(deg, 0, NN*sizeof(int), stream);
    hist_kernel<<<(NE+255)/256, 256, 0, stream>>>(edst, deg);
    scan_kernel<<<1, 256, 0, stream>>>(deg, segoff, cursor);
    scatter_kernel<<<(NE+255)/256, 256, 0, stream>>>(esrc, edst, cursor, srcs, dsts);

    float* ys_cur = ys0; float* ys_old = ys1;
    float* yv_cur = yv0; float* yv_old = yv1;
    for (int l = 0; l < 4; ++l) {
        edge_fused_kernel<<<NE/64, 256, 0, stream>>>(
            x_pad, srcs, dsts,
            w1bp + (size_t)l*64*32,  fc_b1 + (size_t)l*64,
            w2bp + (size_t)l*64*64,  fc_b2 + (size_t)l*64,
            w3bf + (size_t)l*192*64, fc_b3 + (size_t)l*192,
            fsb, fvvb, ebuf);
        segsum_kernel<<<NN/16, 256, 0, stream>>>(ebuf, segoff, midb);
        int ln = (l + 1) & 3;   // next-layer lin1 weights (l=3: dummy but valid)
        node_update_kernel<<<NN, 256, 0, stream>>>(
            ys_cur, yv_cur, ys_old, yv_old,
            midb, types,
            scsT   + (size_t)l*100*5120, scvT   + (size_t)l*100*256,
            lin2sT + (size_t)l*100*1280, lin2vT + (size_t)l*100*1280,
            siWsT  + (size_t)l*4096,     siWvT  + (size_t)l*256,
            lin1sT + (size_t)ln*100*4096, lin1vT + (size_t)ln*100*256,
            Kbuf, hv, mixv, l, fsb, fvvb,
            x_pad, (l == 3) ? (float*)d_out : nullptr);
        float* tmp;
        tmp = ys_cur; ys_cur = ys_old; ys_old = tmp;
        tmp = yv_cur; yv_cur = yv_old; yv_old = tmp;
    }
}